// Round 1
// baseline (4023.149 us; speedup 1.0000x reference)
//
#include <hip/hip_runtime.h>

#define N_ 50000
#define E_ 800000
#define T_ 800000
#define G_ 64
#define H_ 128

__device__ __forceinline__ float siluf(float v) {
    return __fdividef(v, 1.0f + __expf(-v));
}

// ---------------- CSR build ----------------
__global__ __launch_bounds__(256) void k_count(const int* __restrict__ col, int* deg, int n) {
    int e = blockIdx.x * 256 + threadIdx.x;
    if (e < n) atomicAdd(&deg[col[e]], 1);
}

__global__ __launch_bounds__(1024) void k_scan(const int* __restrict__ deg, int* rowptr, int* cur, int n) {
    __shared__ int wsum[16];
    __shared__ int s_carry;
    int tid = threadIdx.x, lane = tid & 63, w = tid >> 6;
    if (tid == 0) s_carry = 0;
    __syncthreads();
    for (int base = 0; base < n; base += 1024) {
        int i = base + tid;
        int v = (i < n) ? deg[i] : 0;
        int incl = v;
        #pragma unroll
        for (int s = 1; s < 64; s <<= 1) {
            int t = __shfl_up(incl, (unsigned)s, 64);
            if (lane >= s) incl += t;
        }
        if (lane == 63) wsum[w] = incl;
        __syncthreads();
        int carry0 = s_carry;
        int wexcl = 0;
        for (int j = 0; j < w; ++j) wexcl += wsum[j];
        int excl = carry0 + wexcl + (incl - v);
        if (i < n) { rowptr[i] = excl; cur[i] = excl; }
        __syncthreads();
        if (tid == 1023) s_carry = carry0 + wexcl + incl;
        __syncthreads();
    }
    if (tid == 0) rowptr[n] = s_carry;
}

__global__ __launch_bounds__(256) void k_fill(const int* __restrict__ col, int* cur, int* elist, int n) {
    int e = blockIdx.x * 256 + threadIdx.x;
    if (e < n) {
        int pos = atomicAdd(&cur[col[e]], 1);
        elist[pos] = e;
    }
}

// ---------------- precompute rbf_e ----------------
__global__ __launch_bounds__(256) void k_rbf(const float* __restrict__ dist, const float* __restrict__ freq,
                                             float* __restrict__ rbfE, int n) {
    int e = blockIdx.x * 256 + threadIdx.x;
    if (e >= n) return;
    float d = dist[e] * 0.2f;
    float d2 = d * d, d4 = d2 * d2, d5 = d4 * d;
    float env = __fdividef(1.0f, d) - 28.0f * d5 + 48.0f * d5 * d - 21.0f * d5 * d2;
    #pragma unroll
    for (int r = 0; r < 6; ++r) rbfE[e * 6 + r] = env * __sinf(freq[r] * d);
}

// ---------------- x = atom_table[z] ----------------
__global__ __launch_bounds__(256) void k_init_x(const float* __restrict__ atab, const int* __restrict__ z,
                                                float* __restrict__ x, int n) {
    int t = blockIdx.x * 256 + threadIdx.x;
    if (t >= n * 32) return;
    int node = t >> 5, q = t & 31;
    ((float4*)x)[t] = ((const float4*)atab)[z[node] * 32 + q];
}

// ---------------- SS[n] = sum_{e in n} silu(rbf_e @ w1 + b1) ----------------
__global__ __launch_bounds__(256) void k_embS(const int* __restrict__ rowptr, const int* __restrict__ elist,
                                              const float* __restrict__ rbfE, const float* __restrict__ w1,
                                              const float* __restrict__ b1, float* __restrict__ SS, int n) {
    int node = blockIdx.x * 4 + (threadIdx.x >> 6);
    int lane = threadIdx.x & 63;
    if (node >= n) return;
    int c = lane * 2;
    float wc0[6], wc1[6];
    #pragma unroll
    for (int r = 0; r < 6; ++r) { wc0[r] = w1[r * 128 + c]; wc1[r] = w1[r * 128 + c + 1]; }
    float bb0 = b1[c], bb1 = b1[c + 1];
    float a0 = 0.f, a1 = 0.f;
    int p0 = rowptr[node], p1 = rowptr[node + 1];
    for (int p = p0; p < p1; ++p) {
        int e = elist[p];
        const float* rb = &rbfE[e * 6];
        float r0 = rb[0], r1 = rb[1], r2 = rb[2], r3 = rb[3], r4 = rb[4], r5 = rb[5];
        float u0 = bb0 + r0 * wc0[0] + r1 * wc0[1] + r2 * wc0[2] + r3 * wc0[3] + r4 * wc0[4] + r5 * wc0[5];
        float u1 = bb1 + r0 * wc1[0] + r1 * wc1[1] + r2 * wc1[2] + r3 * wc1[3] + r4 * wc1[4] + r5 * wc1[5];
        a0 += siluf(u0);
        a1 += siluf(u1);
    }
    SS[node * 128 + c] = a0;
    SS[node * 128 + c + 1] = a1;
}

// ---------------- GEMM: C = act(A @ W + bias*scale) [+ C] ; A:(M,128) W:(128,128) ----------------
// BIAS_MODE: 0=none, 1=bias, 2=bias*deg[row]
template <int BIAS_MODE, bool SILU, bool ACC>
__global__ __launch_bounds__(256, 2) void k_gemm(const float* __restrict__ A, const float* __restrict__ W,
                                                 const float* __restrict__ bias, const int* __restrict__ deg,
                                                 float* __restrict__ C, int M) {
    __shared__ float Wl[128 * 128];
    int tid = threadIdx.x;
    {
        const float4* W4 = (const float4*)W;
        float4* Wl4 = (float4*)Wl;
        #pragma unroll
        for (int i = 0; i < 16; ++i) Wl4[i * 256 + tid] = W4[i * 256 + tid];
    }
    int c0 = (tid & 15) * 8;
    int rg = tid >> 4;
    int row0 = blockIdx.x * 128 + rg * 8;
    float bias_c[8];
    if constexpr (BIAS_MODE != 0) {
        #pragma unroll
        for (int j = 0; j < 8; ++j) bias_c[j] = bias[c0 + j];
    }
    const float* Ar[8];
    #pragma unroll
    for (int r = 0; r < 8; ++r) {
        int rr = row0 + r;
        if (rr > M - 1) rr = M - 1;
        Ar[r] = A + (size_t)rr * 128;
    }
    __syncthreads();
    float acc[8][8];
    #pragma unroll
    for (int r = 0; r < 8; ++r)
        #pragma unroll
        for (int j = 0; j < 8; ++j) acc[r][j] = 0.f;

    for (int k0 = 0; k0 < 128; k0 += 4) {
        float4 av[8];
        #pragma unroll
        for (int r = 0; r < 8; ++r) av[r] = *(const float4*)(Ar[r] + k0);
        #pragma unroll
        for (int kk = 0; kk < 4; ++kk) {
            float4 w0 = *(float4*)&Wl[(k0 + kk) * 128 + c0];
            float4 w1 = *(float4*)&Wl[(k0 + kk) * 128 + c0 + 4];
            #pragma unroll
            for (int r = 0; r < 8; ++r) {
                float a_ = ((float*)&av[r])[kk];
                acc[r][0] += a_ * w0.x; acc[r][1] += a_ * w0.y;
                acc[r][2] += a_ * w0.z; acc[r][3] += a_ * w0.w;
                acc[r][4] += a_ * w1.x; acc[r][5] += a_ * w1.y;
                acc[r][6] += a_ * w1.z; acc[r][7] += a_ * w1.w;
            }
        }
    }
    #pragma unroll
    for (int r = 0; r < 8; ++r) {
        int row = row0 + r;
        if (row >= M) break;
        float scale = 1.f;
        if constexpr (BIAS_MODE == 2) scale = (float)deg[row];
        float vout[8];
        #pragma unroll
        for (int j = 0; j < 8; ++j) {
            float v = acc[r][j];
            if constexpr (BIAS_MODE != 0) v += bias_c[j] * scale;
            if constexpr (SILU) v = siluf(v);
            vout[j] = v;
        }
        float* Cr = &C[(size_t)row * 128 + c0];
        if constexpr (ACC) {
            float4 o0 = *(float4*)&Cr[0], o1 = *(float4*)&Cr[4];
            vout[0] += o0.x; vout[1] += o0.y; vout[2] += o0.z; vout[3] += o0.w;
            vout[4] += o1.x; vout[5] += o1.y; vout[6] += o1.z; vout[7] += o1.w;
        }
        *(float4*)&Cr[0] = make_float4(vout[0], vout[1], vout[2], vout[3]);
        *(float4*)&Cr[4] = make_float4(vout[4], vout[5], vout[6], vout[7]);
    }
}

// ---------------- out_block gather: h[n] = sum_{e in n} x[row_e] * (rbf_e @ ow_rbf) ----------------
__global__ __launch_bounds__(256) void k_out_gather(const int* __restrict__ rowptr, const int* __restrict__ elist,
                                                    const int* __restrict__ erow, const float* __restrict__ rbfE,
                                                    const float* __restrict__ x, const float* __restrict__ wrbf,
                                                    float* __restrict__ h, int n) {
    int node = blockIdx.x * 4 + (threadIdx.x >> 6);
    int lane = threadIdx.x & 63;
    if (node >= n) return;
    int c = lane * 2;
    float wc0[6], wc1[6];
    #pragma unroll
    for (int r = 0; r < 6; ++r) { wc0[r] = wrbf[r * 128 + c]; wc1[r] = wrbf[r * 128 + c + 1]; }
    float a0 = 0.f, a1 = 0.f;
    int p0 = rowptr[node], p1 = rowptr[node + 1];
    for (int p = p0; p < p1; ++p) {
        int e = elist[p];
        int src = erow[e];
        const float* rb = &rbfE[e * 6];
        float r0 = rb[0], r1 = rb[1], r2 = rb[2], r3 = rb[3], r4 = rb[4], r5 = rb[5];
        float e0 = r0 * wc0[0] + r1 * wc0[1] + r2 * wc0[2] + r3 * wc0[3] + r4 * wc0[4] + r5 * wc0[5];
        float e1 = r0 * wc1[0] + r1 * wc1[1] + r2 * wc1[2] + r3 * wc1[3] + r4 * wc1[4] + r5 * wc1[5];
        float2 xv = *(const float2*)&x[(size_t)src * 128 + c];
        a0 += xv.x * e0;
        a1 += xv.y * e1;
    }
    h[node * 128 + c] = a0;
    h[node * 128 + c + 1] = a1;
}

// ---------------- P accumulate: P[n] (+)= h[n] . w2col + ob2 ----------------
template <bool ACC>
__global__ __launch_bounds__(256) void k_p_acc(const float* __restrict__ h, const float* __restrict__ w2col,
                                               const float* __restrict__ ob2p, float* __restrict__ P, int n) {
    int node = blockIdx.x * 4 + (threadIdx.x >> 6);
    int lane = threadIdx.x & 63;
    if (node >= n) return;
    int c = lane * 2;
    float2 hv = *(const float2*)&h[(size_t)node * 128 + c];
    float s = hv.x * w2col[c] + hv.y * w2col[c + 1];
    #pragma unroll
    for (int off = 32; off > 0; off >>= 1) s += __shfl_xor(s, off, 64);
    if (lane == 0) {
        float r = s + ob2p[0];
        if (ACC) r += P[node];
        P[node] = r;
    }
}

// ---------------- triplet: SV[j] += silu(sbf_t @ iw_sbf1) (8 channels) ----------------
__global__ __launch_bounds__(256) void k_triplet_sv(const float* __restrict__ dist_trip, const float* __restrict__ angle,
                                                    const int* __restrict__ trip, const float* __restrict__ sfreq,
                                                    const float* __restrict__ W1, float* __restrict__ SV, int n) {
    __shared__ float W1s[192];
    int tid = threadIdx.x;
    if (tid < 192) W1s[tid] = W1[tid];
    __syncthreads();
    int t = blockIdx.x * 256 + tid;
    if (t >= n) return;
    float d = dist_trip[t] * 0.2f;
    float d2 = d * d, d4 = d2 * d2, d5 = d4 * d;
    float env = __fdividef(1.0f, d) - 28.0f * d5 + 48.0f * d5 * d - 21.0f * d5 * d2;
    float rb[6];
    #pragma unroll
    for (int r = 0; r < 6; ++r) rb[r] = env * __sinf(sfreq[r] * d);
    float a = angle[t];
    float sph[4];
    sph[0] = 1.0f; sph[1] = a; sph[2] = 1.5f * a * a - 0.5f; sph[3] = 2.5f * a * a * a - 1.5f * a;
    float acc[8];
    #pragma unroll
    for (int k = 0; k < 8; ++k) acc[k] = 0.f;
    #pragma unroll
    for (int s = 0; s < 4; ++s) {
        #pragma unroll
        for (int r = 0; r < 6; ++r) {
            float p = sph[s] * rb[r];
            const float* wr = &W1s[(s * 6 + r) * 8];
            #pragma unroll
            for (int k = 0; k < 8; ++k) acc[k] += p * wr[k];
        }
    }
    int j = trip[3 * t + 1];
    #pragma unroll
    for (int k = 0; k < 8; ++k) atomicAdd(&SV[j * 8 + k], siluf(acc[k]));
}

// ---------------- e2 = SV @ iw_sbf2 : (N,8)@(8,128) ----------------
__global__ __launch_bounds__(256) void k_sv_gemm(const float* __restrict__ SV, const float* __restrict__ W2,
                                                 float* __restrict__ e2, int n) {
    __shared__ float W2s[8 * 128];
    int tid = threadIdx.x;
    for (int i = tid; i < 1024; i += 256) W2s[i] = W2[i];
    __syncthreads();
    int t = blockIdx.x * 256 + tid;
    if (t >= n * 32) return;
    int node = t >> 5, q = t & 31;
    const float* sv = &SV[node * 8];
    int c = q * 4;
    float out[4] = {0.f, 0.f, 0.f, 0.f};
    #pragma unroll
    for (int k = 0; k < 8; ++k) {
        float s = sv[k];
        #pragma unroll
        for (int i = 0; i < 4; ++i) out[i] += s * W2s[k * 128 + c + i];
    }
    *(float4*)&e2[(size_t)node * 128 + c] = make_float4(out[0], out[1], out[2], out[3]);
}

// ---------------- extra[c] = sum_n t_mat[n][c] * e2[n][c] ----------------
__global__ __launch_bounds__(256) void k_extra_reduce(const float* __restrict__ Tm, const float* __restrict__ E2,
                                                      float* __restrict__ extra, int n) {
    const float4* t4 = (const float4*)Tm;
    const float4* e4 = (const float4*)E2;
    int tid = threadIdx.x;
    int q = tid & 31, rl = tid >> 5;
    float ax = 0.f, ay = 0.f, az = 0.f, aw = 0.f;
    for (int nn = blockIdx.x * 8 + rl; nn < n; nn += 1024) {
        float4 a = t4[(size_t)nn * 32 + q];
        float4 b = e4[(size_t)nn * 32 + q];
        ax += a.x * b.x; ay += a.y * b.y; az += a.z * b.z; aw += a.w * b.w;
    }
    __shared__ float4 red[256];
    red[tid] = make_float4(ax, ay, az, aw);
    __syncthreads();
    if (tid < 128) {
        float4 o = red[tid + 128];
        red[tid].x += o.x; red[tid].y += o.y; red[tid].z += o.z; red[tid].w += o.w;
    }
    __syncthreads();
    if (tid < 64) {
        float4 o = red[tid + 64];
        red[tid].x += o.x; red[tid].y += o.y; red[tid].z += o.z; red[tid].w += o.w;
    }
    __syncthreads();
    if (tid < 32) {
        float4 r = red[tid];
        float4 o = red[tid + 32];
        r.x += o.x; r.y += o.y; r.z += o.z; r.w += o.w;
        atomicAdd(&extra[tid * 4 + 0], r.x);
        atomicAdd(&extra[tid * 4 + 1], r.y);
        atomicAdd(&extra[tid * 4 + 2], r.z);
        atomicAdd(&extra[tid * 4 + 3], r.w);
    }
}

// ---------------- interaction: x[n] += sum_{e in n} x_up[row_e]*rbf_emb(e) + deg[n]*extra ----------------
__global__ __launch_bounds__(256) void k_interact(const int* __restrict__ rowptr, const int* __restrict__ elist,
                                                  const int* __restrict__ erow, const float* __restrict__ rbfE,
                                                  const float* __restrict__ xup, const float* __restrict__ W1,
                                                  const float* __restrict__ W2, const float* __restrict__ extra,
                                                  float* __restrict__ x, int n) {
    __shared__ float W1s[48];
    int tid = threadIdx.x;
    if (tid < 48) W1s[tid] = W1[tid];
    __syncthreads();
    int node = blockIdx.x * 4 + (tid >> 6);
    int lane = tid & 63;
    if (node >= n) return;
    int c = lane * 2;
    float w2c0[8], w2c1[8];
    #pragma unroll
    for (int k = 0; k < 8; ++k) { w2c0[k] = W2[k * 128 + c]; w2c1[k] = W2[k * 128 + c + 1]; }
    int p0 = rowptr[node], p1 = rowptr[node + 1];
    float cntf = (float)(p1 - p0);
    float a0 = cntf * extra[c], a1 = cntf * extra[c + 1];
    int kk = lane & 7;
    for (int p = p0; p < p1; ++p) {
        int e = elist[p];
        int src = erow[e];
        const float* rb = &rbfE[e * 6];
        float r0 = rb[0], r1 = rb[1], r2 = rb[2], r3 = rb[3], r4 = rb[4], r5 = rb[5];
        float u = r0 * W1s[0 * 8 + kk] + r1 * W1s[1 * 8 + kk] + r2 * W1s[2 * 8 + kk] +
                  r3 * W1s[3 * 8 + kk] + r4 * W1s[4 * 8 + kk] + r5 * W1s[5 * 8 + kk];
        u = siluf(u);
        float e0 = 0.f, e1 = 0.f;
        #pragma unroll
        for (int k = 0; k < 8; ++k) {
            float vk = __shfl(u, k, 64);
            e0 += vk * w2c0[k];
            e1 += vk * w2c1[k];
        }
        float2 xv = *(const float2*)&xup[(size_t)src * 128 + c];
        a0 += xv.x * e0;
        a1 += xv.y * e1;
    }
    x[(size_t)node * 128 + c] += a0;
    x[(size_t)node * 128 + c + 1] += a1;
}

// ---------------- pooling ----------------
__global__ __launch_bounds__(256) void k_pool(const float* __restrict__ P, const int* __restrict__ batch,
                                              float* __restrict__ pool, float* __restrict__ cnt, int n) {
    int i = blockIdx.x * 256 + threadIdx.x;
    int lane = threadIdx.x & 63;
    int b = (i < n) ? batch[i] : -1;
    float p = (i < n) ? P[i] : 0.f;
    int b0 = __shfl(b, 0, 64);
    int b63 = __shfl(b, 63, 64);
    if (b0 == b63 && b0 >= 0) {
        float s = p;
        #pragma unroll
        for (int off = 32; off > 0; off >>= 1) s += __shfl_xor(s, off, 64);
        if (lane == 0) {
            atomicAdd(&pool[b0], s);
            atomicAdd(&cnt[b0], 64.0f);
        }
    } else {
        if (i < n) {
            atomicAdd(&pool[b], p);
            atomicAdd(&cnt[b], 1.0f);
        }
    }
}

__global__ __launch_bounds__(64) void k_final(const float* __restrict__ pool, const float* __restrict__ cnt,
                                              float* __restrict__ out) {
    int g = threadIdx.x;
    if (g < G_) out[g] = __fdividef(pool[g], fmaxf(cnt[g], 1.0f));
}

extern "C" void kernel_launch(void* const* d_in, const int* in_sizes, int n_in,
                              void* d_out, int out_size, void* d_ws, size_t ws_size,
                              hipStream_t stream) {
    (void)in_sizes; (void)n_in; (void)out_size; (void)ws_size;
    const int* z = (const int*)d_in[0];
    const float* dist = (const float*)d_in[1];
    const float* dist_trip = (const float*)d_in[2];
    const float* angle = (const float*)d_in[3];
    const int* edge_index = (const int*)d_in[4];
    const int* triplets = (const int*)d_in[5];
    const int* batch = (const int*)d_in[6];
    const float* atom_table = (const float*)d_in[7];
    const float* rbf_freq = (const float*)d_in[8];
    const float* sbf_freq = (const float*)d_in[9];
    const float* emb_w1 = (const float*)d_in[10];
    const float* emb_b1 = (const float*)d_in[11];
    const float* emb_w2 = (const float*)d_in[12];
    const float* emb_b2 = (const float*)d_in[13];
    const float* iw_rbf1 = (const float*)d_in[14];
    const float* iw_rbf2 = (const float*)d_in[15];
    const float* iw_sbf1 = (const float*)d_in[16];
    const float* iw_sbf2 = (const float*)d_in[17];
    const float* iw_t1 = (const float*)d_in[18];
    const float* iw_t2 = (const float*)d_in[19];
    const float* ib_t2 = (const float*)d_in[20];
    const float* iw_up = (const float*)d_in[21];
    const float* ib_up = (const float*)d_in[22];
    const float* iw_down = (const float*)d_in[23];
    const float* ib_down = (const float*)d_in[24];
    const float* ow_rbf = (const float*)d_in[25];
    const float* ow0 = (const float*)d_in[26];
    const float* ob0 = (const float*)d_in[27];
    const float* ow1 = (const float*)d_in[28];
    const float* ob1 = (const float*)d_in[29];
    const float* ow2 = (const float*)d_in[30];
    const float* ob2 = (const float*)d_in[31];

    const int* erow = edge_index;       // row
    const int* ecol = edge_index + E_;  // col

    // workspace layout
    float* ws = (float*)d_ws;
    float* x = ws;                             // N*128
    float* bufA = x + (size_t)N_ * H_;         // N*128
    float* bufB = bufA + (size_t)N_ * H_;      // N*128
    float* P = bufB + (size_t)N_ * H_;         // N
    float* rbfE = P + N_;                      // E*6
    float* SV = rbfE + (size_t)E_ * 6;         // N*8
    float* extra = SV + (size_t)N_ * 8;        // 128
    float* pool = extra + 128;                 // G
    float* cnt = pool + G_;                    // G
    int* deg = (int*)(cnt + G_);               // N
    int* rowptr = deg + N_;                    // N+1
    int* cur = rowptr + N_ + 1;                // N
    int* elist = cur + N_;                     // E

    const int EG = (E_ + 255) / 256;       // 3125
    const int NG4 = (N_ + 3) / 4;          // 12500
    const int GEMMG = (N_ + 127) / 128;    // 391

    // CSR build (col is identical for every segment_sum in the model)
    hipMemsetAsync(deg, 0, N_ * sizeof(int), stream);
    k_count<<<EG, 256, 0, stream>>>(ecol, deg, E_);
    k_scan<<<1, 1024, 0, stream>>>(deg, rowptr, cur, N_);
    k_fill<<<EG, 256, 0, stream>>>(ecol, cur, elist, E_);
    k_rbf<<<EG, 256, 0, stream>>>(dist, rbf_freq, rbfE, E_);
    k_init_x<<<(N_ * 32) / 256, 256, 0, stream>>>(atom_table, z, x, N_);

    // embedding: x += segsum(silu(rbf@w1+b1)) @ w2 + deg*b2
    k_embS<<<NG4, 256, 0, stream>>>(rowptr, elist, rbfE, emb_w1, emb_b1, bufA, N_);
    k_gemm<2, false, true><<<GEMMG, 256, 0, stream>>>(bufA, emb_w2, emb_b2, deg, x, N_);

    auto out_block = [&](int k, bool first) {
        k_out_gather<<<NG4, 256, 0, stream>>>(rowptr, elist, erow, rbfE, x,
                                              ow_rbf + (size_t)k * 6 * 128, bufA, N_);
        k_gemm<1, true, false><<<GEMMG, 256, 0, stream>>>(bufA, ow0 + (size_t)k * 16384, ob0 + k * 128,
                                                          nullptr, bufB, N_);
        k_gemm<1, true, false><<<GEMMG, 256, 0, stream>>>(bufB, ow1 + (size_t)k * 16384, ob1 + k * 128,
                                                          nullptr, bufA, N_);
        if (first)
            k_p_acc<false><<<NG4, 256, 0, stream>>>(bufA, ow2 + k * 128, ob2 + k, P, N_);
        else
            k_p_acc<true><<<NG4, 256, 0, stream>>>(bufA, ow2 + k * 128, ob2 + k, P, N_);
    };

    out_block(0, true);

    for (int b = 0; b < 4; ++b) {
        // t = silu(x_down @ t1) @ t2 + ib_t2
        k_gemm<1, false, false><<<GEMMG, 256, 0, stream>>>(x, iw_down + (size_t)b * 16384, ib_down + b * 128,
                                                           nullptr, bufA, N_);
        k_gemm<0, true, false><<<GEMMG, 256, 0, stream>>>(bufA, iw_t1 + (size_t)b * 16384, nullptr,
                                                          nullptr, bufB, N_);
        k_gemm<1, false, false><<<GEMMG, 256, 0, stream>>>(bufB, iw_t2 + (size_t)b * 16384, ib_t2 + b * 128,
                                                           nullptr, bufA, N_);
        // extra = sum_t t[j]⊙sbf_emb = sum_n t[n]⊙(SV[n]@W2)
        hipMemsetAsync(SV, 0, (size_t)N_ * 8 * sizeof(float), stream);
        k_triplet_sv<<<(T_ + 255) / 256, 256, 0, stream>>>(dist_trip, angle, triplets, sbf_freq,
                                                           iw_sbf1 + (size_t)b * 192, SV, T_);
        k_sv_gemm<<<(N_ * 32) / 256, 256, 0, stream>>>(SV, iw_sbf2 + (size_t)b * 1024, bufB, N_);
        hipMemsetAsync(extra, 0, 128 * sizeof(float), stream);
        k_extra_reduce<<<128, 256, 0, stream>>>(bufA, bufB, extra, N_);
        // x_up then x += segsum(x_up[row]*rbf_emb + extra)
        k_gemm<1, false, false><<<GEMMG, 256, 0, stream>>>(x, iw_up + (size_t)b * 16384, ib_up + b * 128,
                                                           nullptr, bufB, N_);
        k_interact<<<NG4, 256, 0, stream>>>(rowptr, elist, erow, rbfE, bufB,
                                            iw_rbf1 + (size_t)b * 48, iw_rbf2 + (size_t)b * 1024, extra, x, N_);
        out_block(b + 1, false);
    }

    hipMemsetAsync(pool, 0, 2 * G_ * sizeof(float), stream);
    k_pool<<<(N_ + 255) / 256, 256, 0, stream>>>(P, batch, pool, cnt, N_);
    k_final<<<1, 64, 0, stream>>>(pool, cnt, (float*)d_out);
}

// Round 2
// 2958.965 us; speedup vs baseline: 1.3596x; 1.3596x over previous
//
#include <hip/hip_runtime.h>

#define N_ 50000
#define E_ 800000
#define T_ 800000
#define G_ 64
#define H_ 128

__device__ __forceinline__ float siluf(float v) {
    return __fdividef(v, 1.0f + __expf(-v));
}

// ---------------- CSR build ----------------
__global__ __launch_bounds__(256) void k_count(const int* __restrict__ col, int* deg, int n) {
    int e = blockIdx.x * 256 + threadIdx.x;
    if (e < n) atomicAdd(&deg[col[e]], 1);
}

// count over triplets[:,1] (stride-3 layout)
__global__ __launch_bounds__(256) void k_countT(const int* __restrict__ trip, int* deg, int n) {
    int t = blockIdx.x * 256 + threadIdx.x;
    if (t < n) atomicAdd(&deg[trip[3 * t + 1]], 1);
}

__global__ __launch_bounds__(1024) void k_scan(const int* __restrict__ deg, int* rowptr, int* cur, int n) {
    __shared__ int wsum[16];
    __shared__ int s_carry;
    int tid = threadIdx.x, lane = tid & 63, w = tid >> 6;
    if (tid == 0) s_carry = 0;
    __syncthreads();
    for (int base = 0; base < n; base += 1024) {
        int i = base + tid;
        int v = (i < n) ? deg[i] : 0;
        int incl = v;
        #pragma unroll
        for (int s = 1; s < 64; s <<= 1) {
            int t = __shfl_up(incl, (unsigned)s, 64);
            if (lane >= s) incl += t;
        }
        if (lane == 63) wsum[w] = incl;
        __syncthreads();
        int carry0 = s_carry;
        int wexcl = 0;
        for (int j = 0; j < w; ++j) wexcl += wsum[j];
        int excl = carry0 + wexcl + (incl - v);
        if (i < n) { rowptr[i] = excl; cur[i] = excl; }
        __syncthreads();
        if (tid == 1023) s_carry = carry0 + wexcl + incl;
        __syncthreads();
    }
    if (tid == 0) rowptr[n] = s_carry;
}

__global__ __launch_bounds__(256) void k_fill(const int* __restrict__ col, int* cur, int* elist, int n) {
    int e = blockIdx.x * 256 + threadIdx.x;
    if (e < n) {
        int pos = atomicAdd(&cur[col[e]], 1);
        elist[pos] = e;
    }
}

// fill for triplets: sort the payload (dist_trip, angle) into segment order, no index list needed
__global__ __launch_bounds__(256) void k_fillT(const int* __restrict__ trip, int* cur,
                                               const float* __restrict__ dist_trip, const float* __restrict__ angle,
                                               float* __restrict__ dsort, float* __restrict__ asort, int n) {
    int t = blockIdx.x * 256 + threadIdx.x;
    if (t < n) {
        int pos = atomicAdd(&cur[trip[3 * t + 1]], 1);
        dsort[pos] = dist_trip[t];
        asort[pos] = angle[t];
    }
}

// ---------------- precompute rbf_e ----------------
__global__ __launch_bounds__(256) void k_rbf(const float* __restrict__ dist, const float* __restrict__ freq,
                                             float* __restrict__ rbfE, int n) {
    int e = blockIdx.x * 256 + threadIdx.x;
    if (e >= n) return;
    float d = dist[e] * 0.2f;
    float d2 = d * d, d4 = d2 * d2, d5 = d4 * d;
    float env = __fdividef(1.0f, d) - 28.0f * d5 + 48.0f * d5 * d - 21.0f * d5 * d2;
    #pragma unroll
    for (int r = 0; r < 6; ++r) rbfE[e * 6 + r] = env * __sinf(freq[r] * d);
}

// ---------------- x = atom_table[z] ----------------
__global__ __launch_bounds__(256) void k_init_x(const float* __restrict__ atab, const int* __restrict__ z,
                                                float* __restrict__ x, int n) {
    int t = blockIdx.x * 256 + threadIdx.x;
    if (t >= n * 32) return;
    int node = t >> 5, q = t & 31;
    ((float4*)x)[t] = ((const float4*)atab)[z[node] * 32 + q];
}

// ---------------- SS[n] = sum_{e in n} silu(rbf_e @ w1 + b1) ----------------
__global__ __launch_bounds__(256) void k_embS(const int* __restrict__ rowptr, const int* __restrict__ elist,
                                              const float* __restrict__ rbfE, const float* __restrict__ w1,
                                              const float* __restrict__ b1, float* __restrict__ SS, int n) {
    int node = blockIdx.x * 4 + (threadIdx.x >> 6);
    int lane = threadIdx.x & 63;
    if (node >= n) return;
    int c = lane * 2;
    float wc0[6], wc1[6];
    #pragma unroll
    for (int r = 0; r < 6; ++r) { wc0[r] = w1[r * 128 + c]; wc1[r] = w1[r * 128 + c + 1]; }
    float bb0 = b1[c], bb1 = b1[c + 1];
    float a0 = 0.f, a1 = 0.f;
    int p0 = rowptr[node], p1 = rowptr[node + 1];
    for (int p = p0; p < p1; ++p) {
        int e = elist[p];
        const float* rb = &rbfE[e * 6];
        float r0 = rb[0], r1 = rb[1], r2 = rb[2], r3 = rb[3], r4 = rb[4], r5 = rb[5];
        float u0 = bb0 + r0 * wc0[0] + r1 * wc0[1] + r2 * wc0[2] + r3 * wc0[3] + r4 * wc0[4] + r5 * wc0[5];
        float u1 = bb1 + r0 * wc1[0] + r1 * wc1[1] + r2 * wc1[2] + r3 * wc1[3] + r4 * wc1[4] + r5 * wc1[5];
        a0 += siluf(u0);
        a1 += siluf(u1);
    }
    SS[node * 128 + c] = a0;
    SS[node * 128 + c + 1] = a1;
}

// ---------------- GEMM: C = act(A @ W + bias*scale) [+ C] ; A:(M,128) W:(128,128) ----------------
// BIAS_MODE: 0=none, 1=bias, 2=bias*deg[row]
template <int BIAS_MODE, bool SILU, bool ACC>
__global__ __launch_bounds__(256, 2) void k_gemm(const float* __restrict__ A, const float* __restrict__ W,
                                                 const float* __restrict__ bias, const int* __restrict__ deg,
                                                 float* __restrict__ C, int M) {
    __shared__ float Wl[128 * 128];
    int tid = threadIdx.x;
    {
        const float4* W4 = (const float4*)W;
        float4* Wl4 = (float4*)Wl;
        #pragma unroll
        for (int i = 0; i < 16; ++i) Wl4[i * 256 + tid] = W4[i * 256 + tid];
    }
    int c0 = (tid & 15) * 8;
    int rg = tid >> 4;
    int row0 = blockIdx.x * 128 + rg * 8;
    float bias_c[8];
    if constexpr (BIAS_MODE != 0) {
        #pragma unroll
        for (int j = 0; j < 8; ++j) bias_c[j] = bias[c0 + j];
    }
    const float* Ar[8];
    #pragma unroll
    for (int r = 0; r < 8; ++r) {
        int rr = row0 + r;
        if (rr > M - 1) rr = M - 1;
        Ar[r] = A + (size_t)rr * 128;
    }
    __syncthreads();
    float acc[8][8];
    #pragma unroll
    for (int r = 0; r < 8; ++r)
        #pragma unroll
        for (int j = 0; j < 8; ++j) acc[r][j] = 0.f;

    for (int k0 = 0; k0 < 128; k0 += 4) {
        float4 av[8];
        #pragma unroll
        for (int r = 0; r < 8; ++r) av[r] = *(const float4*)(Ar[r] + k0);
        #pragma unroll
        for (int kk = 0; kk < 4; ++kk) {
            float4 w0 = *(float4*)&Wl[(k0 + kk) * 128 + c0];
            float4 w1 = *(float4*)&Wl[(k0 + kk) * 128 + c0 + 4];
            #pragma unroll
            for (int r = 0; r < 8; ++r) {
                float a_ = ((float*)&av[r])[kk];
                acc[r][0] += a_ * w0.x; acc[r][1] += a_ * w0.y;
                acc[r][2] += a_ * w0.z; acc[r][3] += a_ * w0.w;
                acc[r][4] += a_ * w1.x; acc[r][5] += a_ * w1.y;
                acc[r][6] += a_ * w1.z; acc[r][7] += a_ * w1.w;
            }
        }
    }
    #pragma unroll
    for (int r = 0; r < 8; ++r) {
        int row = row0 + r;
        if (row >= M) break;
        float scale = 1.f;
        if constexpr (BIAS_MODE == 2) scale = (float)deg[row];
        float vout[8];
        #pragma unroll
        for (int j = 0; j < 8; ++j) {
            float v = acc[r][j];
            if constexpr (BIAS_MODE != 0) v += bias_c[j] * scale;
            if constexpr (SILU) v = siluf(v);
            vout[j] = v;
        }
        float* Cr = &C[(size_t)row * 128 + c0];
        if constexpr (ACC) {
            float4 o0 = *(float4*)&Cr[0], o1 = *(float4*)&Cr[4];
            vout[0] += o0.x; vout[1] += o0.y; vout[2] += o0.z; vout[3] += o0.w;
            vout[4] += o1.x; vout[5] += o1.y; vout[6] += o1.z; vout[7] += o1.w;
        }
        *(float4*)&Cr[0] = make_float4(vout[0], vout[1], vout[2], vout[3]);
        *(float4*)&Cr[4] = make_float4(vout[4], vout[5], vout[6], vout[7]);
    }
}

// ---------------- out_block gather: h[n] = sum_{e in n} x[row_e] * (rbf_e @ ow_rbf) ----------------
__global__ __launch_bounds__(256) void k_out_gather(const int* __restrict__ rowptr, const int* __restrict__ elist,
                                                    const int* __restrict__ erow, const float* __restrict__ rbfE,
                                                    const float* __restrict__ x, const float* __restrict__ wrbf,
                                                    float* __restrict__ h, int n) {
    int node = blockIdx.x * 4 + (threadIdx.x >> 6);
    int lane = threadIdx.x & 63;
    if (node >= n) return;
    int c = lane * 2;
    float wc0[6], wc1[6];
    #pragma unroll
    for (int r = 0; r < 6; ++r) { wc0[r] = wrbf[r * 128 + c]; wc1[r] = wrbf[r * 128 + c + 1]; }
    float a0 = 0.f, a1 = 0.f;
    int p0 = rowptr[node], p1 = rowptr[node + 1];
    for (int p = p0; p < p1; ++p) {
        int e = elist[p];
        int src = erow[e];
        const float* rb = &rbfE[e * 6];
        float r0 = rb[0], r1 = rb[1], r2 = rb[2], r3 = rb[3], r4 = rb[4], r5 = rb[5];
        float e0 = r0 * wc0[0] + r1 * wc0[1] + r2 * wc0[2] + r3 * wc0[3] + r4 * wc0[4] + r5 * wc0[5];
        float e1 = r0 * wc1[0] + r1 * wc1[1] + r2 * wc1[2] + r3 * wc1[3] + r4 * wc1[4] + r5 * wc1[5];
        float2 xv = *(const float2*)&x[(size_t)src * 128 + c];
        a0 += xv.x * e0;
        a1 += xv.y * e1;
    }
    h[node * 128 + c] = a0;
    h[node * 128 + c + 1] = a1;
}

// ---------------- P accumulate: P[n] (+)= h[n] . w2col + ob2 ----------------
template <bool ACC>
__global__ __launch_bounds__(256) void k_p_acc(const float* __restrict__ h, const float* __restrict__ w2col,
                                               const float* __restrict__ ob2p, float* __restrict__ P, int n) {
    int node = blockIdx.x * 4 + (threadIdx.x >> 6);
    int lane = threadIdx.x & 63;
    if (node >= n) return;
    int c = lane * 2;
    float2 hv = *(const float2*)&h[(size_t)node * 128 + c];
    float s = hv.x * w2col[c] + hv.y * w2col[c + 1];
    #pragma unroll
    for (int off = 32; off > 0; off >>= 1) s += __shfl_xor(s, off, 64);
    if (lane == 0) {
        float r = s + ob2p[0];
        if (ACC) r += P[node];
        P[node] = r;
    }
}

// ---------------- triplet SV via CSR gather: SV[j][k] = sum_{p in seg(j)} silu(basis(p) . W1[:,k]) ----------------
// 8 lanes per node; lane k owns channel k (W1 column in 24 registers). dsort/asort are
// the triplet payloads pre-sorted into segment order (no atomics, no index indirection).
__global__ __launch_bounds__(256) void k_trip_sv(const int* __restrict__ rowptrT, const float* __restrict__ dsort,
                                                 const float* __restrict__ asort, const float* __restrict__ sfreq,
                                                 const float* __restrict__ W1, float* __restrict__ SV, int n) {
    int grp = (blockIdx.x * 256 + threadIdx.x) >> 3;  // node
    int k = threadIdx.x & 7;                          // channel
    if (grp >= n) return;
    float w[24];
    #pragma unroll
    for (int i = 0; i < 24; ++i) w[i] = W1[i * 8 + k];
    float f0 = sfreq[0], f1 = sfreq[1], f2 = sfreq[2], f3 = sfreq[3], f4 = sfreq[4], f5 = sfreq[5];
    float acc = 0.f;
    int p0 = rowptrT[grp], p1 = rowptrT[grp + 1];
    for (int p = p0; p < p1; ++p) {
        float d = dsort[p] * 0.2f;
        float a = asort[p];
        float d2 = d * d, d4 = d2 * d2, d5 = d4 * d;
        float env = __fdividef(1.0f, d) - 28.0f * d5 + 48.0f * d5 * d - 21.0f * d5 * d2;
        float rb0 = env * __sinf(f0 * d), rb1 = env * __sinf(f1 * d), rb2 = env * __sinf(f2 * d);
        float rb3 = env * __sinf(f3 * d), rb4 = env * __sinf(f4 * d), rb5 = env * __sinf(f5 * d);
        float s1 = a, s2 = 1.5f * a * a - 0.5f, s3 = 2.5f * a * a * a - 1.5f * a;
        float u = rb0 * w[0] + rb1 * w[1] + rb2 * w[2] + rb3 * w[3] + rb4 * w[4] + rb5 * w[5];
        u += s1 * (rb0 * w[6] + rb1 * w[7] + rb2 * w[8] + rb3 * w[9] + rb4 * w[10] + rb5 * w[11]);
        u += s2 * (rb0 * w[12] + rb1 * w[13] + rb2 * w[14] + rb3 * w[15] + rb4 * w[16] + rb5 * w[17]);
        u += s3 * (rb0 * w[18] + rb1 * w[19] + rb2 * w[20] + rb3 * w[21] + rb4 * w[22] + rb5 * w[23]);
        acc += siluf(u);
    }
    SV[grp * 8 + k] = acc;
}

// ---------------- e2 = SV @ iw_sbf2 : (N,8)@(8,128) ----------------
__global__ __launch_bounds__(256) void k_sv_gemm(const float* __restrict__ SV, const float* __restrict__ W2,
                                                 float* __restrict__ e2, int n) {
    __shared__ float W2s[8 * 128];
    int tid = threadIdx.x;
    for (int i = tid; i < 1024; i += 256) W2s[i] = W2[i];
    __syncthreads();
    int t = blockIdx.x * 256 + tid;
    if (t >= n * 32) return;
    int node = t >> 5, q = t & 31;
    const float* sv = &SV[node * 8];
    int c = q * 4;
    float out[4] = {0.f, 0.f, 0.f, 0.f};
    #pragma unroll
    for (int k = 0; k < 8; ++k) {
        float s = sv[k];
        #pragma unroll
        for (int i = 0; i < 4; ++i) out[i] += s * W2s[k * 128 + c + i];
    }
    *(float4*)&e2[(size_t)node * 128 + c] = make_float4(out[0], out[1], out[2], out[3]);
}

// ---------------- extra[c] = sum_n t_mat[n][c] * e2[n][c] ----------------
__global__ __launch_bounds__(256) void k_extra_reduce(const float* __restrict__ Tm, const float* __restrict__ E2,
                                                      float* __restrict__ extra, int n) {
    const float4* t4 = (const float4*)Tm;
    const float4* e4 = (const float4*)E2;
    int tid = threadIdx.x;
    int q = tid & 31, rl = tid >> 5;
    float ax = 0.f, ay = 0.f, az = 0.f, aw = 0.f;
    for (int nn = blockIdx.x * 8 + rl; nn < n; nn += 1024) {
        float4 a = t4[(size_t)nn * 32 + q];
        float4 b = e4[(size_t)nn * 32 + q];
        ax += a.x * b.x; ay += a.y * b.y; az += a.z * b.z; aw += a.w * b.w;
    }
    __shared__ float4 red[256];
    red[tid] = make_float4(ax, ay, az, aw);
    __syncthreads();
    if (tid < 128) {
        float4 o = red[tid + 128];
        red[tid].x += o.x; red[tid].y += o.y; red[tid].z += o.z; red[tid].w += o.w;
    }
    __syncthreads();
    if (tid < 64) {
        float4 o = red[tid + 64];
        red[tid].x += o.x; red[tid].y += o.y; red[tid].z += o.z; red[tid].w += o.w;
    }
    __syncthreads();
    if (tid < 32) {
        float4 r = red[tid];
        float4 o = red[tid + 32];
        r.x += o.x; r.y += o.y; r.z += o.z; r.w += o.w;
        atomicAdd(&extra[tid * 4 + 0], r.x);
        atomicAdd(&extra[tid * 4 + 1], r.y);
        atomicAdd(&extra[tid * 4 + 2], r.z);
        atomicAdd(&extra[tid * 4 + 3], r.w);
    }
}

// ---------------- interaction: x[n] += sum_{e in n} x_up[row_e]*rbf_emb(e) + deg[n]*extra ----------------
__global__ __launch_bounds__(256) void k_interact(const int* __restrict__ rowptr, const int* __restrict__ elist,
                                                  const int* __restrict__ erow, const float* __restrict__ rbfE,
                                                  const float* __restrict__ xup, const float* __restrict__ W1,
                                                  const float* __restrict__ W2, const float* __restrict__ extra,
                                                  float* __restrict__ x, int n) {
    __shared__ float W1s[48];
    int tid = threadIdx.x;
    if (tid < 48) W1s[tid] = W1[tid];
    __syncthreads();
    int node = blockIdx.x * 4 + (tid >> 6);
    int lane = tid & 63;
    if (node >= n) return;
    int c = lane * 2;
    float w2c0[8], w2c1[8];
    #pragma unroll
    for (int k = 0; k < 8; ++k) { w2c0[k] = W2[k * 128 + c]; w2c1[k] = W2[k * 128 + c + 1]; }
    int p0 = rowptr[node], p1 = rowptr[node + 1];
    float cntf = (float)(p1 - p0);
    float a0 = cntf * extra[c], a1 = cntf * extra[c + 1];
    int kk = lane & 7;
    for (int p = p0; p < p1; ++p) {
        int e = elist[p];
        int src = erow[e];
        const float* rb = &rbfE[e * 6];
        float r0 = rb[0], r1 = rb[1], r2 = rb[2], r3 = rb[3], r4 = rb[4], r5 = rb[5];
        float u = r0 * W1s[0 * 8 + kk] + r1 * W1s[1 * 8 + kk] + r2 * W1s[2 * 8 + kk] +
                  r3 * W1s[3 * 8 + kk] + r4 * W1s[4 * 8 + kk] + r5 * W1s[5 * 8 + kk];
        u = siluf(u);
        float e0 = 0.f, e1 = 0.f;
        #pragma unroll
        for (int k = 0; k < 8; ++k) {
            float vk = __shfl(u, k, 64);
            e0 += vk * w2c0[k];
            e1 += vk * w2c1[k];
        }
        float2 xv = *(const float2*)&xup[(size_t)src * 128 + c];
        a0 += xv.x * e0;
        a1 += xv.y * e1;
    }
    x[(size_t)node * 128 + c] += a0;
    x[(size_t)node * 128 + c + 1] += a1;
}

// ---------------- pooling ----------------
__global__ __launch_bounds__(256) void k_pool(const float* __restrict__ P, const int* __restrict__ batch,
                                              float* __restrict__ pool, float* __restrict__ cnt, int n) {
    int i = blockIdx.x * 256 + threadIdx.x;
    int lane = threadIdx.x & 63;
    int b = (i < n) ? batch[i] : -1;
    float p = (i < n) ? P[i] : 0.f;
    int b0 = __shfl(b, 0, 64);
    int b63 = __shfl(b, 63, 64);
    if (b0 == b63 && b0 >= 0) {
        float s = p;
        #pragma unroll
        for (int off = 32; off > 0; off >>= 1) s += __shfl_xor(s, off, 64);
        if (lane == 0) {
            atomicAdd(&pool[b0], s);
            atomicAdd(&cnt[b0], 64.0f);
        }
    } else {
        if (i < n) {
            atomicAdd(&pool[b], p);
            atomicAdd(&cnt[b], 1.0f);
        }
    }
}

__global__ __launch_bounds__(64) void k_final(const float* __restrict__ pool, const float* __restrict__ cnt,
                                              float* __restrict__ out) {
    int g = threadIdx.x;
    if (g < G_) out[g] = __fdividef(pool[g], fmaxf(cnt[g], 1.0f));
}

extern "C" void kernel_launch(void* const* d_in, const int* in_sizes, int n_in,
                              void* d_out, int out_size, void* d_ws, size_t ws_size,
                              hipStream_t stream) {
    (void)in_sizes; (void)n_in; (void)out_size; (void)ws_size;
    const int* z = (const int*)d_in[0];
    const float* dist = (const float*)d_in[1];
    const float* dist_trip = (const float*)d_in[2];
    const float* angle = (const float*)d_in[3];
    const int* edge_index = (const int*)d_in[4];
    const int* triplets = (const int*)d_in[5];
    const int* batch = (const int*)d_in[6];
    const float* atom_table = (const float*)d_in[7];
    const float* rbf_freq = (const float*)d_in[8];
    const float* sbf_freq = (const float*)d_in[9];
    const float* emb_w1 = (const float*)d_in[10];
    const float* emb_b1 = (const float*)d_in[11];
    const float* emb_w2 = (const float*)d_in[12];
    const float* emb_b2 = (const float*)d_in[13];
    const float* iw_rbf1 = (const float*)d_in[14];
    const float* iw_rbf2 = (const float*)d_in[15];
    const float* iw_sbf1 = (const float*)d_in[16];
    const float* iw_sbf2 = (const float*)d_in[17];
    const float* iw_t1 = (const float*)d_in[18];
    const float* iw_t2 = (const float*)d_in[19];
    const float* ib_t2 = (const float*)d_in[20];
    const float* iw_up = (const float*)d_in[21];
    const float* ib_up = (const float*)d_in[22];
    const float* iw_down = (const float*)d_in[23];
    const float* ib_down = (const float*)d_in[24];
    const float* ow_rbf = (const float*)d_in[25];
    const float* ow0 = (const float*)d_in[26];
    const float* ob0 = (const float*)d_in[27];
    const float* ow1 = (const float*)d_in[28];
    const float* ob1 = (const float*)d_in[29];
    const float* ow2 = (const float*)d_in[30];
    const float* ob2 = (const float*)d_in[31];

    const int* erow = edge_index;       // row
    const int* ecol = edge_index + E_;  // col

    // workspace layout
    float* ws = (float*)d_ws;
    float* x = ws;                             // N*128
    float* bufA = x + (size_t)N_ * H_;         // N*128
    float* bufB = bufA + (size_t)N_ * H_;      // N*128
    float* P = bufB + (size_t)N_ * H_;         // N
    float* rbfE = P + N_;                      // E*6
    float* SV = rbfE + (size_t)E_ * 6;         // N*8
    float* extra = SV + (size_t)N_ * 8;        // 128
    float* pool = extra + 128;                 // G
    float* cnt = pool + G_;                    // G
    int* deg = (int*)(cnt + G_);               // N
    int* rowptr = deg + N_;                    // N+1
    int* cur = rowptr + N_ + 1;                // N (shared by both CSR fills)
    int* elist = cur + N_;                     // E
    int* rowptrT = elist + E_;                 // N+1
    int* degT = rowptrT + N_ + 1;              // N
    float* dsort = (float*)(degT + N_);        // T
    float* asort = dsort + T_;                 // T

    const int EG = (E_ + 255) / 256;       // 3125
    const int TG = (T_ + 255) / 256;       // 3125
    const int NG4 = (N_ + 3) / 4;          // 12500
    const int GEMMG = (N_ + 127) / 128;    // 391

    // CSR over edge col (identical for every edge segment_sum)
    hipMemsetAsync(deg, 0, N_ * sizeof(int), stream);
    hipMemsetAsync(degT, 0, N_ * sizeof(int), stream);
    k_count<<<EG, 256, 0, stream>>>(ecol, deg, E_);
    k_countT<<<TG, 256, 0, stream>>>(triplets, degT, T_);
    k_scan<<<1, 1024, 0, stream>>>(deg, rowptr, cur, N_);
    k_fill<<<EG, 256, 0, stream>>>(ecol, cur, elist, E_);
    // CSR over triplet j_idx; payload (dist_trip, angle) sorted into segment order
    k_scan<<<1, 1024, 0, stream>>>(degT, rowptrT, cur, N_);
    k_fillT<<<TG, 256, 0, stream>>>(triplets, cur, dist_trip, angle, dsort, asort, T_);

    k_rbf<<<EG, 256, 0, stream>>>(dist, rbf_freq, rbfE, E_);
    k_init_x<<<(N_ * 32) / 256, 256, 0, stream>>>(atom_table, z, x, N_);

    // embedding: x += segsum(silu(rbf@w1+b1)) @ w2 + deg*b2
    k_embS<<<NG4, 256, 0, stream>>>(rowptr, elist, rbfE, emb_w1, emb_b1, bufA, N_);
    k_gemm<2, false, true><<<GEMMG, 256, 0, stream>>>(bufA, emb_w2, emb_b2, deg, x, N_);

    auto out_block = [&](int k, bool first) {
        k_out_gather<<<NG4, 256, 0, stream>>>(rowptr, elist, erow, rbfE, x,
                                              ow_rbf + (size_t)k * 6 * 128, bufA, N_);
        k_gemm<1, true, false><<<GEMMG, 256, 0, stream>>>(bufA, ow0 + (size_t)k * 16384, ob0 + k * 128,
                                                          nullptr, bufB, N_);
        k_gemm<1, true, false><<<GEMMG, 256, 0, stream>>>(bufB, ow1 + (size_t)k * 16384, ob1 + k * 128,
                                                          nullptr, bufA, N_);
        if (first)
            k_p_acc<false><<<NG4, 256, 0, stream>>>(bufA, ow2 + k * 128, ob2 + k, P, N_);
        else
            k_p_acc<true><<<NG4, 256, 0, stream>>>(bufA, ow2 + k * 128, ob2 + k, P, N_);
    };

    out_block(0, true);

    for (int b = 0; b < 4; ++b) {
        // t = silu(x_down @ t1) @ t2 + ib_t2
        k_gemm<1, false, false><<<GEMMG, 256, 0, stream>>>(x, iw_down + (size_t)b * 16384, ib_down + b * 128,
                                                           nullptr, bufA, N_);
        k_gemm<0, true, false><<<GEMMG, 256, 0, stream>>>(bufA, iw_t1 + (size_t)b * 16384, nullptr,
                                                          nullptr, bufB, N_);
        k_gemm<1, false, false><<<GEMMG, 256, 0, stream>>>(bufB, iw_t2 + (size_t)b * 16384, ib_t2 + b * 128,
                                                           nullptr, bufA, N_);
        // extra = sum_t t[j]⊙sbf_emb = sum_n t[n]⊙(SV[n]@W2); SV via sorted CSR gather (no atomics)
        k_trip_sv<<<(N_ * 8 + 255) / 256, 256, 0, stream>>>(rowptrT, dsort, asort, sbf_freq,
                                                            iw_sbf1 + (size_t)b * 192, SV, N_);
        k_sv_gemm<<<(N_ * 32) / 256, 256, 0, stream>>>(SV, iw_sbf2 + (size_t)b * 1024, bufB, N_);
        hipMemsetAsync(extra, 0, 128 * sizeof(float), stream);
        k_extra_reduce<<<128, 256, 0, stream>>>(bufA, bufB, extra, N_);
        // x_up then x += segsum(x_up[row]*rbf_emb + extra)
        k_gemm<1, false, false><<<GEMMG, 256, 0, stream>>>(x, iw_up + (size_t)b * 16384, ib_up + b * 128,
                                                           nullptr, bufB, N_);
        k_interact<<<NG4, 256, 0, stream>>>(rowptr, elist, erow, rbfE, bufB,
                                            iw_rbf1 + (size_t)b * 48, iw_rbf2 + (size_t)b * 1024, extra, x, N_);
        out_block(b + 1, false);
    }

    hipMemsetAsync(pool, 0, 2 * G_ * sizeof(float), stream);
    k_pool<<<(N_ + 255) / 256, 256, 0, stream>>>(P, batch, pool, cnt, N_);
    k_final<<<1, 64, 0, stream>>>(pool, cnt, (float*)d_out);
}

// Round 3
// 2508.338 us; speedup vs baseline: 1.6039x; 1.1797x over previous
//
#include <hip/hip_runtime.h>
#include <hip/hip_fp16.h>

#define N_ 50000
#define E_ 800000
#define T_ 800000
#define G_ 64
#define H_ 128

__device__ __forceinline__ float siluf(float v) {
    return __fdividef(v, 1.0f + __expf(-v));
}

// ---------------- CSR build ----------------
__global__ __launch_bounds__(256) void k_count(const int* __restrict__ col, int* deg, int n) {
    int e = blockIdx.x * 256 + threadIdx.x;
    if (e < n) atomicAdd(&deg[col[e]], 1);
}

__global__ __launch_bounds__(256) void k_countT(const int* __restrict__ trip, int* deg, int n) {
    int t = blockIdx.x * 256 + threadIdx.x;
    if (t < n) atomicAdd(&deg[trip[3 * t + 1]], 1);
}

__global__ __launch_bounds__(1024) void k_scan(const int* __restrict__ deg, int* rowptr, int* cur, int n) {
    __shared__ int wsum[16];
    __shared__ int s_carry;
    int tid = threadIdx.x, lane = tid & 63, w = tid >> 6;
    if (tid == 0) s_carry = 0;
    __syncthreads();
    for (int base = 0; base < n; base += 1024) {
        int i = base + tid;
        int v = (i < n) ? deg[i] : 0;
        int incl = v;
        #pragma unroll
        for (int s = 1; s < 64; s <<= 1) {
            int t = __shfl_up(incl, (unsigned)s, 64);
            if (lane >= s) incl += t;
        }
        if (lane == 63) wsum[w] = incl;
        __syncthreads();
        int carry0 = s_carry;
        int wexcl = 0;
        for (int j = 0; j < w; ++j) wexcl += wsum[j];
        int excl = carry0 + wexcl + (incl - v);
        if (i < n) { rowptr[i] = excl; cur[i] = excl; }
        __syncthreads();
        if (tid == 1023) s_carry = carry0 + wexcl + incl;
        __syncthreads();
    }
    if (tid == 0) rowptr[n] = s_carry;
}

// fill edge CSR: elist (edge id, for rbf sort) + slist (pre-resolved source node)
__global__ __launch_bounds__(256) void k_fill(const int* __restrict__ col, const int* __restrict__ row,
                                              int* cur, int* elist, int* slist, int n) {
    int e = blockIdx.x * 256 + threadIdx.x;
    if (e < n) {
        int pos = atomicAdd(&cur[col[e]], 1);
        elist[pos] = e;
        slist[pos] = row[e];
    }
}

// fill triplet CSR: payload (dist_trip, angle) sorted into segment order
__global__ __launch_bounds__(256) void k_fillT(const int* __restrict__ trip, int* cur,
                                               const float* __restrict__ dist_trip, const float* __restrict__ angle,
                                               float* __restrict__ dsort, float* __restrict__ asort, int n) {
    int t = blockIdx.x * 256 + threadIdx.x;
    if (t < n) {
        int pos = atomicAdd(&cur[trip[3 * t + 1]], 1);
        dsort[pos] = dist_trip[t];
        asort[pos] = angle[t];
    }
}

// ---------------- rbf in CSR (segment) order: rbfS[p] = rbf(dist[elist[p]]) ----------------
__global__ __launch_bounds__(256) void k_rbfS(const int* __restrict__ elist, const float* __restrict__ dist,
                                              const float* __restrict__ freq, float* __restrict__ rbfS, int n) {
    int p = blockIdx.x * 256 + threadIdx.x;
    if (p >= n) return;
    int e = elist[p];
    float d = dist[e] * 0.2f;
    float d2 = d * d, d4 = d2 * d2, d5 = d4 * d;
    float env = __fdividef(1.0f, d) - 28.0f * d5 + 48.0f * d5 * d - 21.0f * d5 * d2;
    #pragma unroll
    for (int r = 0; r < 6; ++r) rbfS[p * 6 + r] = env * __sinf(freq[r] * d);
}

// ---------------- per-block edge factors: s8h[p][k] = silu(rbfS[p] . W1[:,k]), fp16 ----------------
__global__ __launch_bounds__(256) void k_s8h(const float* __restrict__ rbfS, const float* __restrict__ W1,
                                             __half* __restrict__ s8, int n) {
    __shared__ float W1s[48];
    int tid = threadIdx.x;
    if (tid < 48) W1s[tid] = W1[tid];
    __syncthreads();
    int p = blockIdx.x * 256 + tid;
    if (p >= n) return;
    float rb[6];
    #pragma unroll
    for (int r = 0; r < 6; ++r) rb[r] = rbfS[p * 6 + r];
    __half out[8];
    #pragma unroll
    for (int k = 0; k < 8; ++k) {
        float u = 0.f;
        #pragma unroll
        for (int r = 0; r < 6; ++r) u += rb[r] * W1s[r * 8 + k];
        out[k] = __float2half(siluf(u));
    }
    *(uint4*)&s8[(size_t)p * 8] = *(uint4*)out;
}

// ---------------- x = atom_table[z] ----------------
__global__ __launch_bounds__(256) void k_init_x(const float* __restrict__ atab, const int* __restrict__ z,
                                                float* __restrict__ x, int n) {
    int t = blockIdx.x * 256 + threadIdx.x;
    if (t >= n * 32) return;
    int node = t >> 5, q = t & 31;
    ((float4*)x)[t] = ((const float4*)atab)[z[node] * 32 + q];
}

// ---------------- SS[n] = sum_{e in n} silu(rbf_e @ w1 + b1) (streams rbfS) ----------------
__global__ __launch_bounds__(256) void k_embS(const int* __restrict__ rowptr, const float* __restrict__ rbfS,
                                              const float* __restrict__ w1, const float* __restrict__ b1,
                                              float* __restrict__ SS, int n) {
    int node = blockIdx.x * 4 + (threadIdx.x >> 6);
    int lane = threadIdx.x & 63;
    if (node >= n) return;
    int c = lane * 2;
    float wc0[6], wc1[6];
    #pragma unroll
    for (int r = 0; r < 6; ++r) { wc0[r] = w1[r * 128 + c]; wc1[r] = w1[r * 128 + c + 1]; }
    float bb0 = b1[c], bb1 = b1[c + 1];
    float a0 = 0.f, a1 = 0.f;
    int p0 = rowptr[node], p1 = rowptr[node + 1];
    for (int p = p0; p < p1; ++p) {
        const float* rb = &rbfS[(size_t)p * 6];
        float r0 = rb[0], r1 = rb[1], r2 = rb[2], r3 = rb[3], r4 = rb[4], r5 = rb[5];
        float u0 = bb0 + r0 * wc0[0] + r1 * wc0[1] + r2 * wc0[2] + r3 * wc0[3] + r4 * wc0[4] + r5 * wc0[5];
        float u1 = bb1 + r0 * wc1[0] + r1 * wc1[1] + r2 * wc1[2] + r3 * wc1[3] + r4 * wc1[4] + r5 * wc1[5];
        a0 += siluf(u0);
        a1 += siluf(u1);
    }
    SS[node * 128 + c] = a0;
    SS[node * 128 + c + 1] = a1;
}

// ---------------- GEMM: C = act(A @ W + bias*scale) [+ C] ; A:(M,128) W:(128,128) ----------------
template <int BIAS_MODE, bool SILU, bool ACC>
__global__ __launch_bounds__(256, 2) void k_gemm(const float* __restrict__ A, const float* __restrict__ W,
                                                 const float* __restrict__ bias, const int* __restrict__ deg,
                                                 float* __restrict__ C, int M) {
    __shared__ float Wl[128 * 128];
    int tid = threadIdx.x;
    {
        const float4* W4 = (const float4*)W;
        float4* Wl4 = (float4*)Wl;
        #pragma unroll
        for (int i = 0; i < 16; ++i) Wl4[i * 256 + tid] = W4[i * 256 + tid];
    }
    int c0 = (tid & 15) * 8;
    int rg = tid >> 4;
    int row0 = blockIdx.x * 128 + rg * 8;
    float bias_c[8];
    if constexpr (BIAS_MODE != 0) {
        #pragma unroll
        for (int j = 0; j < 8; ++j) bias_c[j] = bias[c0 + j];
    }
    const float* Ar[8];
    #pragma unroll
    for (int r = 0; r < 8; ++r) {
        int rr = row0 + r;
        if (rr > M - 1) rr = M - 1;
        Ar[r] = A + (size_t)rr * 128;
    }
    __syncthreads();
    float acc[8][8];
    #pragma unroll
    for (int r = 0; r < 8; ++r)
        #pragma unroll
        for (int j = 0; j < 8; ++j) acc[r][j] = 0.f;

    for (int k0 = 0; k0 < 128; k0 += 4) {
        float4 av[8];
        #pragma unroll
        for (int r = 0; r < 8; ++r) av[r] = *(const float4*)(Ar[r] + k0);
        #pragma unroll
        for (int kk = 0; kk < 4; ++kk) {
            float4 w0 = *(float4*)&Wl[(k0 + kk) * 128 + c0];
            float4 w1 = *(float4*)&Wl[(k0 + kk) * 128 + c0 + 4];
            #pragma unroll
            for (int r = 0; r < 8; ++r) {
                float a_ = ((float*)&av[r])[kk];
                acc[r][0] += a_ * w0.x; acc[r][1] += a_ * w0.y;
                acc[r][2] += a_ * w0.z; acc[r][3] += a_ * w0.w;
                acc[r][4] += a_ * w1.x; acc[r][5] += a_ * w1.y;
                acc[r][6] += a_ * w1.z; acc[r][7] += a_ * w1.w;
            }
        }
    }
    #pragma unroll
    for (int r = 0; r < 8; ++r) {
        int row = row0 + r;
        if (row >= M) break;
        float scale = 1.f;
        if constexpr (BIAS_MODE == 2) scale = (float)deg[row];
        float vout[8];
        #pragma unroll
        for (int j = 0; j < 8; ++j) {
            float v = acc[r][j];
            if constexpr (BIAS_MODE != 0) v += bias_c[j] * scale;
            if constexpr (SILU) v = siluf(v);
            vout[j] = v;
        }
        float* Cr = &C[(size_t)row * 128 + c0];
        if constexpr (ACC) {
            float4 o0 = *(float4*)&Cr[0], o1 = *(float4*)&Cr[4];
            vout[0] += o0.x; vout[1] += o0.y; vout[2] += o0.z; vout[3] += o0.w;
            vout[4] += o1.x; vout[5] += o1.y; vout[6] += o1.z; vout[7] += o1.w;
        }
        *(float4*)&Cr[0] = make_float4(vout[0], vout[1], vout[2], vout[3]);
        *(float4*)&Cr[4] = make_float4(vout[4], vout[5], vout[6], vout[7]);
    }
}

// ---------------- out_block gather: h[n] = sum_{p in n} x[slist[p]] * (rbfS[p] @ wrbf) ----------------
__global__ __launch_bounds__(256) void k_out_gather(const int* __restrict__ rowptr, const int* __restrict__ slist,
                                                    const float* __restrict__ rbfS, const float* __restrict__ x,
                                                    const float* __restrict__ wrbf, float* __restrict__ h, int n) {
    int node = blockIdx.x * 4 + (threadIdx.x >> 6);
    int lane = threadIdx.x & 63;
    if (node >= n) return;
    int c = lane * 2;
    float wc0[6], wc1[6];
    #pragma unroll
    for (int r = 0; r < 6; ++r) { wc0[r] = wrbf[r * 128 + c]; wc1[r] = wrbf[r * 128 + c + 1]; }
    float a0 = 0.f, a1 = 0.f;
    int p0 = rowptr[node], p1 = rowptr[node + 1];
    int p = p0;
    for (; p + 4 <= p1; p += 4) {
        int s0 = slist[p], s1 = slist[p + 1], s2 = slist[p + 2], s3 = slist[p + 3];
        float2 xv0 = *(const float2*)&x[(size_t)s0 * 128 + c];
        float2 xv1 = *(const float2*)&x[(size_t)s1 * 128 + c];
        float2 xv2 = *(const float2*)&x[(size_t)s2 * 128 + c];
        float2 xv3 = *(const float2*)&x[(size_t)s3 * 128 + c];
        #pragma unroll
        for (int u = 0; u < 4; ++u) {
            const float* rb = &rbfS[(size_t)(p + u) * 6];
            float r0 = rb[0], r1 = rb[1], r2 = rb[2], r3 = rb[3], r4 = rb[4], r5 = rb[5];
            float e0 = r0 * wc0[0] + r1 * wc0[1] + r2 * wc0[2] + r3 * wc0[3] + r4 * wc0[4] + r5 * wc0[5];
            float e1 = r0 * wc1[0] + r1 * wc1[1] + r2 * wc1[2] + r3 * wc1[3] + r4 * wc1[4] + r5 * wc1[5];
            float2 xv = (u == 0) ? xv0 : (u == 1) ? xv1 : (u == 2) ? xv2 : xv3;
            a0 += xv.x * e0;
            a1 += xv.y * e1;
        }
    }
    for (; p < p1; ++p) {
        int src = slist[p];
        const float* rb = &rbfS[(size_t)p * 6];
        float r0 = rb[0], r1 = rb[1], r2 = rb[2], r3 = rb[3], r4 = rb[4], r5 = rb[5];
        float e0 = r0 * wc0[0] + r1 * wc0[1] + r2 * wc0[2] + r3 * wc0[3] + r4 * wc0[4] + r5 * wc0[5];
        float e1 = r0 * wc1[0] + r1 * wc1[1] + r2 * wc1[2] + r3 * wc1[3] + r4 * wc1[4] + r5 * wc1[5];
        float2 xv = *(const float2*)&x[(size_t)src * 128 + c];
        a0 += xv.x * e0;
        a1 += xv.y * e1;
    }
    h[node * 128 + c] = a0;
    h[node * 128 + c + 1] = a1;
}

// ---------------- P accumulate: P[n] (+)= h[n] . w2col + ob2 ----------------
template <bool ACC>
__global__ __launch_bounds__(256) void k_p_acc(const float* __restrict__ h, const float* __restrict__ w2col,
                                               const float* __restrict__ ob2p, float* __restrict__ P, int n) {
    int node = blockIdx.x * 4 + (threadIdx.x >> 6);
    int lane = threadIdx.x & 63;
    if (node >= n) return;
    int c = lane * 2;
    float2 hv = *(const float2*)&h[(size_t)node * 128 + c];
    float s = hv.x * w2col[c] + hv.y * w2col[c + 1];
    #pragma unroll
    for (int off = 32; off > 0; off >>= 1) s += __shfl_xor(s, off, 64);
    if (lane == 0) {
        float r = s + ob2p[0];
        if (ACC) r += P[node];
        P[node] = r;
    }
}

// ---------------- triplet SV via sorted CSR gather ----------------
__global__ __launch_bounds__(256) void k_trip_sv(const int* __restrict__ rowptrT, const float* __restrict__ dsort,
                                                 const float* __restrict__ asort, const float* __restrict__ sfreq,
                                                 const float* __restrict__ W1, float* __restrict__ SV, int n) {
    int grp = (blockIdx.x * 256 + threadIdx.x) >> 3;  // node
    int k = threadIdx.x & 7;                          // channel
    if (grp >= n) return;
    float w[24];
    #pragma unroll
    for (int i = 0; i < 24; ++i) w[i] = W1[i * 8 + k];
    float f0 = sfreq[0], f1 = sfreq[1], f2 = sfreq[2], f3 = sfreq[3], f4 = sfreq[4], f5 = sfreq[5];
    float acc = 0.f;
    int p0 = rowptrT[grp], p1 = rowptrT[grp + 1];
    for (int p = p0; p < p1; ++p) {
        float d = dsort[p] * 0.2f;
        float a = asort[p];
        float d2 = d * d, d4 = d2 * d2, d5 = d4 * d;
        float env = __fdividef(1.0f, d) - 28.0f * d5 + 48.0f * d5 * d - 21.0f * d5 * d2;
        float rb0 = env * __sinf(f0 * d), rb1 = env * __sinf(f1 * d), rb2 = env * __sinf(f2 * d);
        float rb3 = env * __sinf(f3 * d), rb4 = env * __sinf(f4 * d), rb5 = env * __sinf(f5 * d);
        float s1 = a, s2 = 1.5f * a * a - 0.5f, s3 = 2.5f * a * a * a - 1.5f * a;
        float u = rb0 * w[0] + rb1 * w[1] + rb2 * w[2] + rb3 * w[3] + rb4 * w[4] + rb5 * w[5];
        u += s1 * (rb0 * w[6] + rb1 * w[7] + rb2 * w[8] + rb3 * w[9] + rb4 * w[10] + rb5 * w[11]);
        u += s2 * (rb0 * w[12] + rb1 * w[13] + rb2 * w[14] + rb3 * w[15] + rb4 * w[16] + rb5 * w[17]);
        u += s3 * (rb0 * w[18] + rb1 * w[19] + rb2 * w[20] + rb3 * w[21] + rb4 * w[22] + rb5 * w[23]);
        acc += siluf(u);
    }
    SV[grp * 8 + k] = acc;
}

// ---------------- e2 = SV @ iw_sbf2 : (N,8)@(8,128) ----------------
__global__ __launch_bounds__(256) void k_sv_gemm(const float* __restrict__ SV, const float* __restrict__ W2,
                                                 float* __restrict__ e2, int n) {
    __shared__ float W2s[8 * 128];
    int tid = threadIdx.x;
    for (int i = tid; i < 1024; i += 256) W2s[i] = W2[i];
    __syncthreads();
    int t = blockIdx.x * 256 + tid;
    if (t >= n * 32) return;
    int node = t >> 5, q = t & 31;
    const float* sv = &SV[node * 8];
    int c = q * 4;
    float out[4] = {0.f, 0.f, 0.f, 0.f};
    #pragma unroll
    for (int k = 0; k < 8; ++k) {
        float s = sv[k];
        #pragma unroll
        for (int i = 0; i < 4; ++i) out[i] += s * W2s[k * 128 + c + i];
    }
    *(float4*)&e2[(size_t)node * 128 + c] = make_float4(out[0], out[1], out[2], out[3]);
}

// ---------------- extra[c] = sum_n t_mat[n][c] * e2[n][c] ----------------
__global__ __launch_bounds__(256) void k_extra_reduce(const float* __restrict__ Tm, const float* __restrict__ E2,
                                                      float* __restrict__ extra, int n) {
    const float4* t4 = (const float4*)Tm;
    const float4* e4 = (const float4*)E2;
    int tid = threadIdx.x;
    int q = tid & 31, rl = tid >> 5;
    float ax = 0.f, ay = 0.f, az = 0.f, aw = 0.f;
    for (int nn = blockIdx.x * 8 + rl; nn < n; nn += 1024) {
        float4 a = t4[(size_t)nn * 32 + q];
        float4 b = e4[(size_t)nn * 32 + q];
        ax += a.x * b.x; ay += a.y * b.y; az += a.z * b.z; aw += a.w * b.w;
    }
    __shared__ float4 red[256];
    red[tid] = make_float4(ax, ay, az, aw);
    __syncthreads();
    if (tid < 128) {
        float4 o = red[tid + 128];
        red[tid].x += o.x; red[tid].y += o.y; red[tid].z += o.z; red[tid].w += o.w;
    }
    __syncthreads();
    if (tid < 64) {
        float4 o = red[tid + 64];
        red[tid].x += o.x; red[tid].y += o.y; red[tid].z += o.z; red[tid].w += o.w;
    }
    __syncthreads();
    if (tid < 32) {
        float4 r = red[tid];
        float4 o = red[tid + 32];
        r.x += o.x; r.y += o.y; r.z += o.z; r.w += o.w;
        atomicAdd(&extra[tid * 4 + 0], r.x);
        atomicAdd(&extra[tid * 4 + 1], r.y);
        atomicAdd(&extra[tid * 4 + 2], r.z);
        atomicAdd(&extra[tid * 4 + 3], r.w);
    }
}

// ---------------- interaction: x[n] += sum_{p in n} x_up[slist[p]]*(s8h[p] @ W2) + deg[n]*extra ----------------
__global__ __launch_bounds__(256) void k_interact(const int* __restrict__ rowptr, const int* __restrict__ slist,
                                                  const __half* __restrict__ s8, const float* __restrict__ W2,
                                                  const float* __restrict__ extra, const float* __restrict__ xup,
                                                  float* __restrict__ x, int n) {
    int node = blockIdx.x * 4 + (threadIdx.x >> 6);
    int lane = threadIdx.x & 63;
    if (node >= n) return;
    int c = lane * 2;
    float w2c0[8], w2c1[8];
    #pragma unroll
    for (int k = 0; k < 8; ++k) { w2c0[k] = W2[k * 128 + c]; w2c1[k] = W2[k * 128 + c + 1]; }
    int p0 = rowptr[node], p1 = rowptr[node + 1];
    float cntf = (float)(p1 - p0);
    float a0 = cntf * extra[c], a1 = cntf * extra[c + 1];
    int p = p0;
    for (; p + 4 <= p1; p += 4) {
        int s0 = slist[p], s1 = slist[p + 1], s2 = slist[p + 2], s3 = slist[p + 3];
        float2 xv0 = *(const float2*)&xup[(size_t)s0 * 128 + c];
        float2 xv1 = *(const float2*)&xup[(size_t)s1 * 128 + c];
        float2 xv2 = *(const float2*)&xup[(size_t)s2 * 128 + c];
        float2 xv3 = *(const float2*)&xup[(size_t)s3 * 128 + c];
        #pragma unroll
        for (int u = 0; u < 4; ++u) {
            const __half2* h2 = (const __half2*)(s8 + (size_t)(p + u) * 8);
            float2 s01 = __half22float2(h2[0]);
            float2 s23 = __half22float2(h2[1]);
            float2 s45 = __half22float2(h2[2]);
            float2 s67 = __half22float2(h2[3]);
            float e0 = s01.x * w2c0[0] + s01.y * w2c0[1] + s23.x * w2c0[2] + s23.y * w2c0[3] +
                       s45.x * w2c0[4] + s45.y * w2c0[5] + s67.x * w2c0[6] + s67.y * w2c0[7];
            float e1 = s01.x * w2c1[0] + s01.y * w2c1[1] + s23.x * w2c1[2] + s23.y * w2c1[3] +
                       s45.x * w2c1[4] + s45.y * w2c1[5] + s67.x * w2c1[6] + s67.y * w2c1[7];
            float2 xv = (u == 0) ? xv0 : (u == 1) ? xv1 : (u == 2) ? xv2 : xv3;
            a0 += xv.x * e0;
            a1 += xv.y * e1;
        }
    }
    for (; p < p1; ++p) {
        int src = slist[p];
        float2 xv = *(const float2*)&xup[(size_t)src * 128 + c];
        const __half2* h2 = (const __half2*)(s8 + (size_t)p * 8);
        float2 s01 = __half22float2(h2[0]);
        float2 s23 = __half22float2(h2[1]);
        float2 s45 = __half22float2(h2[2]);
        float2 s67 = __half22float2(h2[3]);
        float e0 = s01.x * w2c0[0] + s01.y * w2c0[1] + s23.x * w2c0[2] + s23.y * w2c0[3] +
                   s45.x * w2c0[4] + s45.y * w2c0[5] + s67.x * w2c0[6] + s67.y * w2c0[7];
        float e1 = s01.x * w2c1[0] + s01.y * w2c1[1] + s23.x * w2c1[2] + s23.y * w2c1[3] +
                   s45.x * w2c1[4] + s45.y * w2c1[5] + s67.x * w2c1[6] + s67.y * w2c1[7];
        a0 += xv.x * e0;
        a1 += xv.y * e1;
    }
    x[(size_t)node * 128 + c] += a0;
    x[(size_t)node * 128 + c + 1] += a1;
}

// ---------------- pooling ----------------
__global__ __launch_bounds__(256) void k_pool(const float* __restrict__ P, const int* __restrict__ batch,
                                              float* __restrict__ pool, float* __restrict__ cnt, int n) {
    int i = blockIdx.x * 256 + threadIdx.x;
    int lane = threadIdx.x & 63;
    int b = (i < n) ? batch[i] : -1;
    float p = (i < n) ? P[i] : 0.f;
    int b0 = __shfl(b, 0, 64);
    int b63 = __shfl(b, 63, 64);
    if (b0 == b63 && b0 >= 0) {
        float s = p;
        #pragma unroll
        for (int off = 32; off > 0; off >>= 1) s += __shfl_xor(s, off, 64);
        if (lane == 0) {
            atomicAdd(&pool[b0], s);
            atomicAdd(&cnt[b0], 64.0f);
        }
    } else {
        if (i < n) {
            atomicAdd(&pool[b], p);
            atomicAdd(&cnt[b], 1.0f);
        }
    }
}

__global__ __launch_bounds__(64) void k_final(const float* __restrict__ pool, const float* __restrict__ cnt,
                                              float* __restrict__ out) {
    int g = threadIdx.x;
    if (g < G_) out[g] = __fdividef(pool[g], fmaxf(cnt[g], 1.0f));
}

extern "C" void kernel_launch(void* const* d_in, const int* in_sizes, int n_in,
                              void* d_out, int out_size, void* d_ws, size_t ws_size,
                              hipStream_t stream) {
    (void)in_sizes; (void)n_in; (void)out_size; (void)ws_size;
    const int* z = (const int*)d_in[0];
    const float* dist = (const float*)d_in[1];
    const float* dist_trip = (const float*)d_in[2];
    const float* angle = (const float*)d_in[3];
    const int* edge_index = (const int*)d_in[4];
    const int* triplets = (const int*)d_in[5];
    const int* batch = (const int*)d_in[6];
    const float* atom_table = (const float*)d_in[7];
    const float* rbf_freq = (const float*)d_in[8];
    const float* sbf_freq = (const float*)d_in[9];
    const float* emb_w1 = (const float*)d_in[10];
    const float* emb_b1 = (const float*)d_in[11];
    const float* emb_w2 = (const float*)d_in[12];
    const float* emb_b2 = (const float*)d_in[13];
    const float* iw_rbf1 = (const float*)d_in[14];
    const float* iw_rbf2 = (const float*)d_in[15];
    const float* iw_sbf1 = (const float*)d_in[16];
    const float* iw_sbf2 = (const float*)d_in[17];
    const float* iw_t1 = (const float*)d_in[18];
    const float* iw_t2 = (const float*)d_in[19];
    const float* ib_t2 = (const float*)d_in[20];
    const float* iw_up = (const float*)d_in[21];
    const float* ib_up = (const float*)d_in[22];
    const float* iw_down = (const float*)d_in[23];
    const float* ib_down = (const float*)d_in[24];
    const float* ow_rbf = (const float*)d_in[25];
    const float* ow0 = (const float*)d_in[26];
    const float* ob0 = (const float*)d_in[27];
    const float* ow1 = (const float*)d_in[28];
    const float* ob1 = (const float*)d_in[29];
    const float* ow2 = (const float*)d_in[30];
    const float* ob2 = (const float*)d_in[31];

    const int* erow = edge_index;       // row
    const int* ecol = edge_index + E_;  // col

    // workspace layout (floats unless noted)
    float* ws = (float*)d_ws;
    float* x = ws;                             // N*128
    float* bufA = x + (size_t)N_ * H_;         // N*128
    float* bufB = bufA + (size_t)N_ * H_;      // N*128
    float* P = bufB + (size_t)N_ * H_;         // N
    float* rbfS = P + N_;                      // E*6 (CSR order)
    float* SV = rbfS + (size_t)E_ * 6;         // N*8
    float* extra = SV + (size_t)N_ * 8;        // 128
    float* pool = extra + 128;                 // G
    float* cnt = pool + G_;                    // G
    int* deg = (int*)(cnt + G_);               // N
    int* rowptr = deg + N_;                    // N+1
    int* cur = rowptr + N_ + 1;                // N (shared by both CSR fills)
    int* elist = cur + N_;                     // E
    int* slist = elist + E_;                   // E (pre-resolved row[e] in CSR order)
    int* rowptrT = slist + E_;                 // N+1
    int* degT = rowptrT + N_ + 1;              // N
    float* dsort = (float*)(degT + N_);        // T
    float* asort = dsort + T_;                 // T
    __half* s8h = (__half*)(asort + T_);       // E*8 halves

    const int EG = (E_ + 255) / 256;       // 3125
    const int TG = (T_ + 255) / 256;       // 3125
    const int NG4 = (N_ + 3) / 4;          // 12500
    const int GEMMG = (N_ + 127) / 128;    // 391

    // CSR over edge col (identical for every edge segment_sum)
    hipMemsetAsync(deg, 0, N_ * sizeof(int), stream);
    hipMemsetAsync(degT, 0, N_ * sizeof(int), stream);
    k_count<<<EG, 256, 0, stream>>>(ecol, deg, E_);
    k_countT<<<TG, 256, 0, stream>>>(triplets, degT, T_);
    k_scan<<<1, 1024, 0, stream>>>(deg, rowptr, cur, N_);
    k_fill<<<EG, 256, 0, stream>>>(ecol, erow, cur, elist, slist, E_);
    k_scan<<<1, 1024, 0, stream>>>(degT, rowptrT, cur, N_);
    k_fillT<<<TG, 256, 0, stream>>>(triplets, cur, dist_trip, angle, dsort, asort, T_);

    k_rbfS<<<EG, 256, 0, stream>>>(elist, dist, rbf_freq, rbfS, E_);
    k_init_x<<<(N_ * 32) / 256, 256, 0, stream>>>(atom_table, z, x, N_);

    // embedding: x += segsum(silu(rbf@w1+b1)) @ w2 + deg*b2
    k_embS<<<NG4, 256, 0, stream>>>(rowptr, rbfS, emb_w1, emb_b1, bufA, N_);
    k_gemm<2, false, true><<<GEMMG, 256, 0, stream>>>(bufA, emb_w2, emb_b2, deg, x, N_);

    auto out_block = [&](int k, bool first) {
        k_out_gather<<<NG4, 256, 0, stream>>>(rowptr, slist, rbfS, x,
                                              ow_rbf + (size_t)k * 6 * 128, bufA, N_);
        k_gemm<1, true, false><<<GEMMG, 256, 0, stream>>>(bufA, ow0 + (size_t)k * 16384, ob0 + k * 128,
                                                          nullptr, bufB, N_);
        k_gemm<1, true, false><<<GEMMG, 256, 0, stream>>>(bufB, ow1 + (size_t)k * 16384, ob1 + k * 128,
                                                          nullptr, bufA, N_);
        if (first)
            k_p_acc<false><<<NG4, 256, 0, stream>>>(bufA, ow2 + k * 128, ob2 + k, P, N_);
        else
            k_p_acc<true><<<NG4, 256, 0, stream>>>(bufA, ow2 + k * 128, ob2 + k, P, N_);
    };

    out_block(0, true);

    for (int b = 0; b < 4; ++b) {
        // t = silu(x_down @ t1) @ t2 + ib_t2
        k_gemm<1, false, false><<<GEMMG, 256, 0, stream>>>(x, iw_down + (size_t)b * 16384, ib_down + b * 128,
                                                           nullptr, bufA, N_);
        k_gemm<0, true, false><<<GEMMG, 256, 0, stream>>>(bufA, iw_t1 + (size_t)b * 16384, nullptr,
                                                          nullptr, bufB, N_);
        k_gemm<1, false, false><<<GEMMG, 256, 0, stream>>>(bufB, iw_t2 + (size_t)b * 16384, ib_t2 + b * 128,
                                                           nullptr, bufA, N_);
        // extra = sum_n t[n]⊙(SV[n]@W2)
        k_trip_sv<<<(N_ * 8 + 255) / 256, 256, 0, stream>>>(rowptrT, dsort, asort, sbf_freq,
                                                            iw_sbf1 + (size_t)b * 192, SV, N_);
        k_sv_gemm<<<(N_ * 32) / 256, 256, 0, stream>>>(SV, iw_sbf2 + (size_t)b * 1024, bufB, N_);
        hipMemsetAsync(extra, 0, 128 * sizeof(float), stream);
        k_extra_reduce<<<128, 256, 0, stream>>>(bufA, bufB, extra, N_);
        // edge factors for this block, then x_up, then fused scatter-gather
        k_s8h<<<EG, 256, 0, stream>>>(rbfS, iw_rbf1 + (size_t)b * 48, s8h, E_);
        k_gemm<1, false, false><<<GEMMG, 256, 0, stream>>>(x, iw_up + (size_t)b * 16384, ib_up + b * 128,
                                                           nullptr, bufB, N_);
        k_interact<<<NG4, 256, 0, stream>>>(rowptr, slist, s8h, iw_rbf2 + (size_t)b * 1024, extra,
                                            bufB, x, N_);
        out_block(b + 1, false);
    }

    hipMemsetAsync(pool, 0, 2 * G_ * sizeof(float), stream);
    k_pool<<<(N_ + 255) / 256, 256, 0, stream>>>(P, batch, pool, cnt, N_);
    k_final<<<1, 64, 0, stream>>>(pool, cnt, (float*)d_out);
}

// Round 5
// 2461.386 us; speedup vs baseline: 1.6345x; 1.0191x over previous
//
#include <hip/hip_runtime.h>
#include <hip/hip_fp16.h>

#define N_ 50000
#define E_ 800000
#define T_ 800000
#define G_ 64
#define H_ 128

__device__ __forceinline__ float siluf(float v) {
    return __fdividef(v, 1.0f + __expf(-v));
}

// bf16 helpers (round-to-nearest-even-ish via bias; range = fp32 range)
__device__ __forceinline__ unsigned short f2bf(float f) {
    unsigned int u = __float_as_uint(f);
    u += 0x7fffu + ((u >> 16) & 1u);
    return (unsigned short)(u >> 16);
}
__device__ __forceinline__ float bf2f(unsigned short h) {
    return __uint_as_float(((unsigned int)h) << 16);
}
__device__ __forceinline__ unsigned int f2bf2(float a, float b) {
    return (unsigned int)f2bf(a) | ((unsigned int)f2bf(b) << 16);
}
__device__ __forceinline__ float2 bf2x2(unsigned int p) {
    return make_float2(__uint_as_float(p << 16), __uint_as_float(p & 0xffff0000u));
}

// ---------------- CSR build ----------------
__global__ __launch_bounds__(256) void k_count(const int* __restrict__ col, int* deg, int n) {
    int e = blockIdx.x * 256 + threadIdx.x;
    if (e < n) atomicAdd(&deg[col[e]], 1);
}

__global__ __launch_bounds__(256) void k_countT(const int* __restrict__ trip, int* deg, int n) {
    int t = blockIdx.x * 256 + threadIdx.x;
    if (t < n) atomicAdd(&deg[trip[3 * t + 1]], 1);
}

__global__ __launch_bounds__(1024) void k_scan(const int* __restrict__ deg, int* rowptr, int* cur, int n) {
    __shared__ int wsum[16];
    __shared__ int s_carry;
    int tid = threadIdx.x, lane = tid & 63, w = tid >> 6;
    if (tid == 0) s_carry = 0;
    __syncthreads();
    for (int base = 0; base < n; base += 1024) {
        int i = base + tid;
        int v = (i < n) ? deg[i] : 0;
        int incl = v;
        #pragma unroll
        for (int s = 1; s < 64; s <<= 1) {
            int t = __shfl_up(incl, (unsigned)s, 64);
            if (lane >= s) incl += t;
        }
        if (lane == 63) wsum[w] = incl;
        __syncthreads();
        int carry0 = s_carry;
        int wexcl = 0;
        for (int j = 0; j < w; ++j) wexcl += wsum[j];
        int excl = carry0 + wexcl + (incl - v);
        if (i < n) { rowptr[i] = excl; cur[i] = excl; }
        __syncthreads();
        if (tid == 1023) s_carry = carry0 + wexcl + incl;
        __syncthreads();
    }
    if (tid == 0) rowptr[n] = s_carry;
}

__global__ __launch_bounds__(256) void k_fill(const int* __restrict__ col, const int* __restrict__ row,
                                              int* cur, int* elist, int* slist, int n) {
    int e = blockIdx.x * 256 + threadIdx.x;
    if (e < n) {
        int pos = atomicAdd(&cur[col[e]], 1);
        elist[pos] = e;
        slist[pos] = row[e];
    }
}

__global__ __launch_bounds__(256) void k_fillT(const int* __restrict__ trip, int* cur,
                                               const float* __restrict__ dist_trip, const float* __restrict__ angle,
                                               float* __restrict__ dsort, float* __restrict__ asort, int n) {
    int t = blockIdx.x * 256 + threadIdx.x;
    if (t < n) {
        int pos = atomicAdd(&cur[trip[3 * t + 1]], 1);
        dsort[pos] = dist_trip[t];
        asort[pos] = angle[t];
    }
}

// ---------------- rbf in CSR (segment) order ----------------
__global__ __launch_bounds__(256) void k_rbfS(const int* __restrict__ elist, const float* __restrict__ dist,
                                              const float* __restrict__ freq, float* __restrict__ rbfS, int n) {
    int p = blockIdx.x * 256 + threadIdx.x;
    if (p >= n) return;
    int e = elist[p];
    float d = dist[e] * 0.2f;
    float d2 = d * d, d4 = d2 * d2, d5 = d4 * d;
    float env = __fdividef(1.0f, d) - 28.0f * d5 + 48.0f * d5 * d - 21.0f * d5 * d2;
    #pragma unroll
    for (int r = 0; r < 6; ++r) rbfS[p * 6 + r] = env * __sinf(freq[r] * d);
}

// ---------------- per-block edge factors: s8h[p][k] = silu(rbfS[p] . W1[:,k]), fp16 ----------------
__global__ __launch_bounds__(256) void k_s8h(const float* __restrict__ rbfS, const float* __restrict__ W1,
                                             __half* __restrict__ s8, int n) {
    __shared__ float W1s[48];
    int tid = threadIdx.x;
    if (tid < 48) W1s[tid] = W1[tid];
    __syncthreads();
    int p = blockIdx.x * 256 + tid;
    if (p >= n) return;
    const float2* r2 = (const float2*)&rbfS[(size_t)p * 6];
    float2 ra = r2[0], rbx = r2[1], rc = r2[2];
    float rb[6] = {ra.x, ra.y, rbx.x, rbx.y, rc.x, rc.y};
    __half out[8];
    #pragma unroll
    for (int k = 0; k < 8; ++k) {
        float u = 0.f;
        #pragma unroll
        for (int r = 0; r < 6; ++r) u += rb[r] * W1s[r * 8 + k];
        out[k] = __float2half(siluf(u));
    }
    *(uint4*)&s8[(size_t)p * 8] = *(uint4*)out;
}

// ---------------- x = atom_table[z] ----------------
__global__ __launch_bounds__(256) void k_init_x(const float* __restrict__ atab, const int* __restrict__ z,
                                                float* __restrict__ x, int n) {
    int t = blockIdx.x * 256 + threadIdx.x;
    if (t >= n * 32) return;
    int node = t >> 5, q = t & 31;
    ((float4*)x)[t] = ((const float4*)atab)[z[node] * 32 + q];
}

// ---------------- SS[n] = sum_{e in n} silu(rbf_e @ w1 + b1) ----------------
__global__ __launch_bounds__(256) void k_embS(const int* __restrict__ rowptr, const float* __restrict__ rbfS,
                                              const float* __restrict__ w1, const float* __restrict__ b1,
                                              float* __restrict__ SS, int n) {
    int node = blockIdx.x * 4 + (threadIdx.x >> 6);
    int lane = threadIdx.x & 63;
    if (node >= n) return;
    int c = lane * 2;
    float wc0[6], wc1[6];
    #pragma unroll
    for (int r = 0; r < 6; ++r) { wc0[r] = w1[r * 128 + c]; wc1[r] = w1[r * 128 + c + 1]; }
    float bb0 = b1[c], bb1 = b1[c + 1];
    float a0 = 0.f, a1 = 0.f;
    int p0 = rowptr[node], p1 = rowptr[node + 1];
    for (int p = p0; p < p1; ++p) {
        const float2* r2 = (const float2*)&rbfS[(size_t)p * 6];
        float2 ra = r2[0], rbx = r2[1], rc = r2[2];
        float r0 = ra.x, r1 = ra.y, r2v = rbx.x, r3 = rbx.y, r4 = rc.x, r5 = rc.y;
        float u0 = bb0 + r0 * wc0[0] + r1 * wc0[1] + r2v * wc0[2] + r3 * wc0[3] + r4 * wc0[4] + r5 * wc0[5];
        float u1 = bb1 + r0 * wc1[0] + r1 * wc1[1] + r2v * wc1[2] + r3 * wc1[3] + r4 * wc1[4] + r5 * wc1[5];
        a0 += siluf(u0);
        a1 += siluf(u1);
    }
    SS[node * 128 + c] = a0;
    SS[node * 128 + c + 1] = a1;
}

// ---------------- GEMM: C = act(A @ W + bias*scale) [+ C] ; optional bf16 shadow copy ----------------
template <int BIAS_MODE, bool SILU, bool ACC, bool WBF>
__global__ __launch_bounds__(256, 2) void k_gemm(const float* __restrict__ A, const float* __restrict__ W,
                                                 const float* __restrict__ bias, const int* __restrict__ deg,
                                                 float* __restrict__ C, unsigned short* __restrict__ Ch, int M) {
    __shared__ float Wl[128 * 128];
    int tid = threadIdx.x;
    {
        const float4* W4 = (const float4*)W;
        float4* Wl4 = (float4*)Wl;
        #pragma unroll
        for (int i = 0; i < 16; ++i) Wl4[i * 256 + tid] = W4[i * 256 + tid];
    }
    int c0 = (tid & 15) * 8;
    int rg = tid >> 4;
    int row0 = blockIdx.x * 128 + rg * 8;
    float bias_c[8];
    if constexpr (BIAS_MODE != 0) {
        #pragma unroll
        for (int j = 0; j < 8; ++j) bias_c[j] = bias[c0 + j];
    }
    const float* Ar[8];
    #pragma unroll
    for (int r = 0; r < 8; ++r) {
        int rr = row0 + r;
        if (rr > M - 1) rr = M - 1;
        Ar[r] = A + (size_t)rr * 128;
    }
    __syncthreads();
    float acc[8][8];
    #pragma unroll
    for (int r = 0; r < 8; ++r)
        #pragma unroll
        for (int j = 0; j < 8; ++j) acc[r][j] = 0.f;

    for (int k0 = 0; k0 < 128; k0 += 4) {
        float4 av[8];
        #pragma unroll
        for (int r = 0; r < 8; ++r) av[r] = *(const float4*)(Ar[r] + k0);
        #pragma unroll
        for (int kk = 0; kk < 4; ++kk) {
            float4 w0 = *(float4*)&Wl[(k0 + kk) * 128 + c0];
            float4 w1 = *(float4*)&Wl[(k0 + kk) * 128 + c0 + 4];
            #pragma unroll
            for (int r = 0; r < 8; ++r) {
                float a_ = ((float*)&av[r])[kk];
                acc[r][0] += a_ * w0.x; acc[r][1] += a_ * w0.y;
                acc[r][2] += a_ * w0.z; acc[r][3] += a_ * w0.w;
                acc[r][4] += a_ * w1.x; acc[r][5] += a_ * w1.y;
                acc[r][6] += a_ * w1.z; acc[r][7] += a_ * w1.w;
            }
        }
    }
    #pragma unroll
    for (int r = 0; r < 8; ++r) {
        int row = row0 + r;
        if (row >= M) break;
        float scale = 1.f;
        if constexpr (BIAS_MODE == 2) scale = (float)deg[row];
        float vout[8];
        #pragma unroll
        for (int j = 0; j < 8; ++j) {
            float v = acc[r][j];
            if constexpr (BIAS_MODE != 0) v += bias_c[j] * scale;
            if constexpr (SILU) v = siluf(v);
            vout[j] = v;
        }
        float* Cr = &C[(size_t)row * 128 + c0];
        if constexpr (ACC) {
            float4 o0 = *(float4*)&Cr[0], o1 = *(float4*)&Cr[4];
            vout[0] += o0.x; vout[1] += o0.y; vout[2] += o0.z; vout[3] += o0.w;
            vout[4] += o1.x; vout[5] += o1.y; vout[6] += o1.z; vout[7] += o1.w;
        }
        *(float4*)&Cr[0] = make_float4(vout[0], vout[1], vout[2], vout[3]);
        *(float4*)&Cr[4] = make_float4(vout[4], vout[5], vout[6], vout[7]);
        if constexpr (WBF) {
            uint4 pk;
            pk.x = f2bf2(vout[0], vout[1]);
            pk.y = f2bf2(vout[2], vout[3]);
            pk.z = f2bf2(vout[4], vout[5]);
            pk.w = f2bf2(vout[6], vout[7]);
            *(uint4*)&Ch[(size_t)row * 128 + c0] = pk;
        }
    }
}

// ---------------- out_block gather: h[n] = sum_{p in n} xh[slist[p]] * (rbfS[p] @ wrbf) ----------------
__global__ __launch_bounds__(256) void k_out_gather(const int* __restrict__ rowptr, const int* __restrict__ slist,
                                                    const float* __restrict__ rbfS,
                                                    const unsigned short* __restrict__ xh,
                                                    const float* __restrict__ wrbf, float* __restrict__ h, int n) {
    int node = blockIdx.x * 4 + (threadIdx.x >> 6);
    int lane = threadIdx.x & 63;
    if (node >= n) return;
    int c = lane * 2;
    float wc0[6], wc1[6];
    #pragma unroll
    for (int r = 0; r < 6; ++r) { wc0[r] = wrbf[r * 128 + c]; wc1[r] = wrbf[r * 128 + c + 1]; }
    float a0 = 0.f, a1 = 0.f;
    int p0 = rowptr[node], p1 = rowptr[node + 1];
    int p = p0;
    for (; p + 4 <= p1; p += 4) {
        int s0 = slist[p], s1 = slist[p + 1], s2 = slist[p + 2], s3 = slist[p + 3];
        float2 rb[4][3];
        #pragma unroll
        for (int u = 0; u < 4; ++u) {
            const float2* r2 = (const float2*)&rbfS[(size_t)(p + u) * 6];
            rb[u][0] = r2[0]; rb[u][1] = r2[1]; rb[u][2] = r2[2];
        }
        unsigned int xv0 = *(const unsigned int*)&xh[(size_t)s0 * 128 + c];
        unsigned int xv1 = *(const unsigned int*)&xh[(size_t)s1 * 128 + c];
        unsigned int xv2 = *(const unsigned int*)&xh[(size_t)s2 * 128 + c];
        unsigned int xv3 = *(const unsigned int*)&xh[(size_t)s3 * 128 + c];
        #pragma unroll
        for (int u = 0; u < 4; ++u) {
            float r0 = rb[u][0].x, r1 = rb[u][0].y, r2v = rb[u][1].x, r3 = rb[u][1].y, r4 = rb[u][2].x, r5 = rb[u][2].y;
            float e0 = r0 * wc0[0] + r1 * wc0[1] + r2v * wc0[2] + r3 * wc0[3] + r4 * wc0[4] + r5 * wc0[5];
            float e1 = r0 * wc1[0] + r1 * wc1[1] + r2v * wc1[2] + r3 * wc1[3] + r4 * wc1[4] + r5 * wc1[5];
            float2 xf = bf2x2((u == 0) ? xv0 : (u == 1) ? xv1 : (u == 2) ? xv2 : xv3);
            a0 += xf.x * e0;
            a1 += xf.y * e1;
        }
    }
    for (; p < p1; ++p) {
        int src = slist[p];
        const float2* r2 = (const float2*)&rbfS[(size_t)p * 6];
        float2 ra = r2[0], rbx = r2[1], rc = r2[2];
        float e0 = ra.x * wc0[0] + ra.y * wc0[1] + rbx.x * wc0[2] + rbx.y * wc0[3] + rc.x * wc0[4] + rc.y * wc0[5];
        float e1 = ra.x * wc1[0] + ra.y * wc1[1] + rbx.x * wc1[2] + rbx.y * wc1[3] + rc.x * wc1[4] + rc.y * wc1[5];
        float2 xf = bf2x2(*(const unsigned int*)&xh[(size_t)src * 128 + c]);
        a0 += xf.x * e0;
        a1 += xf.y * e1;
    }
    h[node * 128 + c] = a0;
    h[node * 128 + c + 1] = a1;
}

// ---------------- P accumulate ----------------
template <bool ACC>
__global__ __launch_bounds__(256) void k_p_acc(const float* __restrict__ h, const float* __restrict__ w2col,
                                               const float* __restrict__ ob2p, float* __restrict__ P, int n) {
    int node = blockIdx.x * 4 + (threadIdx.x >> 6);
    int lane = threadIdx.x & 63;
    if (node >= n) return;
    int c = lane * 2;
    float2 hv = *(const float2*)&h[(size_t)node * 128 + c];
    float s = hv.x * w2col[c] + hv.y * w2col[c + 1];
    #pragma unroll
    for (int off = 32; off > 0; off >>= 1) s += __shfl_xor(s, off, 64);
    if (lane == 0) {
        float r = s + ob2p[0];
        if (ACC) r += P[node];
        P[node] = r;
    }
}

// ---------------- triplet SV via sorted CSR gather ----------------
__global__ __launch_bounds__(256) void k_trip_sv(const int* __restrict__ rowptrT, const float* __restrict__ dsort,
                                                 const float* __restrict__ asort, const float* __restrict__ sfreq,
                                                 const float* __restrict__ W1, float* __restrict__ SV, int n) {
    int grp = (blockIdx.x * 256 + threadIdx.x) >> 3;
    int k = threadIdx.x & 7;
    if (grp >= n) return;
    float w[24];
    #pragma unroll
    for (int i = 0; i < 24; ++i) w[i] = W1[i * 8 + k];
    float f0 = sfreq[0], f1 = sfreq[1], f2 = sfreq[2], f3 = sfreq[3], f4 = sfreq[4], f5 = sfreq[5];
    float acc = 0.f;
    int p0 = rowptrT[grp], p1 = rowptrT[grp + 1];
    for (int p = p0; p < p1; ++p) {
        float d = dsort[p] * 0.2f;
        float a = asort[p];
        float d2 = d * d, d4 = d2 * d2, d5 = d4 * d;
        float env = __fdividef(1.0f, d) - 28.0f * d5 + 48.0f * d5 * d - 21.0f * d5 * d2;
        float rb0 = env * __sinf(f0 * d), rb1 = env * __sinf(f1 * d), rb2 = env * __sinf(f2 * d);
        float rb3 = env * __sinf(f3 * d), rb4 = env * __sinf(f4 * d), rb5 = env * __sinf(f5 * d);
        float s1 = a, s2 = 1.5f * a * a - 0.5f, s3 = 2.5f * a * a * a - 1.5f * a;
        float u = rb0 * w[0] + rb1 * w[1] + rb2 * w[2] + rb3 * w[3] + rb4 * w[4] + rb5 * w[5];
        u += s1 * (rb0 * w[6] + rb1 * w[7] + rb2 * w[8] + rb3 * w[9] + rb4 * w[10] + rb5 * w[11]);
        u += s2 * (rb0 * w[12] + rb1 * w[13] + rb2 * w[14] + rb3 * w[15] + rb4 * w[16] + rb5 * w[17]);
        u += s3 * (rb0 * w[18] + rb1 * w[19] + rb2 * w[20] + rb3 * w[21] + rb4 * w[22] + rb5 * w[23]);
        acc += siluf(u);
    }
    SV[grp * 8 + k] = acc;
}

// ---------------- e2 = SV @ iw_sbf2 ----------------
__global__ __launch_bounds__(256) void k_sv_gemm(const float* __restrict__ SV, const float* __restrict__ W2,
                                                 float* __restrict__ e2, int n) {
    __shared__ float W2s[8 * 128];
    int tid = threadIdx.x;
    for (int i = tid; i < 1024; i += 256) W2s[i] = W2[i];
    __syncthreads();
    int t = blockIdx.x * 256 + tid;
    if (t >= n * 32) return;
    int node = t >> 5, q = t & 31;
    const float* sv = &SV[node * 8];
    int c = q * 4;
    float out[4] = {0.f, 0.f, 0.f, 0.f};
    #pragma unroll
    for (int k = 0; k < 8; ++k) {
        float s = sv[k];
        #pragma unroll
        for (int i = 0; i < 4; ++i) out[i] += s * W2s[k * 128 + c + i];
    }
    *(float4*)&e2[(size_t)node * 128 + c] = make_float4(out[0], out[1], out[2], out[3]);
}

// ---------------- extra[c] = sum_n t_mat[n][c] * e2[n][c] ----------------
__global__ __launch_bounds__(256) void k_extra_reduce(const float* __restrict__ Tm, const float* __restrict__ E2,
                                                      float* __restrict__ extra, int n) {
    const float4* t4 = (const float4*)Tm;
    const float4* e4 = (const float4*)E2;
    int tid = threadIdx.x;
    int q = tid & 31, rl = tid >> 5;
    float ax = 0.f, ay = 0.f, az = 0.f, aw = 0.f;
    for (int nn = blockIdx.x * 8 + rl; nn < n; nn += 1024) {
        float4 a = t4[(size_t)nn * 32 + q];
        float4 b = e4[(size_t)nn * 32 + q];
        ax += a.x * b.x; ay += a.y * b.y; az += a.z * b.z; aw += a.w * b.w;
    }
    __shared__ float4 red[256];
    red[tid] = make_float4(ax, ay, az, aw);
    __syncthreads();
    if (tid < 128) {
        float4 o = red[tid + 128];
        red[tid].x += o.x; red[tid].y += o.y; red[tid].z += o.z; red[tid].w += o.w;
    }
    __syncthreads();
    if (tid < 64) {
        float4 o = red[tid + 64];
        red[tid].x += o.x; red[tid].y += o.y; red[tid].z += o.z; red[tid].w += o.w;
    }
    __syncthreads();
    if (tid < 32) {
        float4 r = red[tid];
        float4 o = red[tid + 32];
        r.x += o.x; r.y += o.y; r.z += o.z; r.w += o.w;
        atomicAdd(&extra[tid * 4 + 0], r.x);
        atomicAdd(&extra[tid * 4 + 1], r.y);
        atomicAdd(&extra[tid * 4 + 2], r.z);
        atomicAdd(&extra[tid * 4 + 3], r.w);
    }
}

// ---------------- interaction: x[n] += sum_{p in n} xuph[slist[p]]*(s8h[p] @ W2) + deg[n]*extra ----------------
// also refreshes the bf16 shadow xh of the updated x.
__global__ __launch_bounds__(256) void k_interact(const int* __restrict__ rowptr, const int* __restrict__ slist,
                                                  const __half* __restrict__ s8, const float* __restrict__ W2,
                                                  const float* __restrict__ extra,
                                                  const unsigned short* __restrict__ xuph,
                                                  float* __restrict__ x, unsigned short* __restrict__ xh, int n) {
    int node = blockIdx.x * 4 + (threadIdx.x >> 6);
    int lane = threadIdx.x & 63;
    if (node >= n) return;
    int c = lane * 2;
    float w2c0[8], w2c1[8];
    #pragma unroll
    for (int k = 0; k < 8; ++k) { w2c0[k] = W2[k * 128 + c]; w2c1[k] = W2[k * 128 + c + 1]; }
    int p0 = rowptr[node], p1 = rowptr[node + 1];
    float cntf = (float)(p1 - p0);
    float a0 = cntf * extra[c], a1 = cntf * extra[c + 1];
    int p = p0;
    for (; p + 4 <= p1; p += 4) {
        int s0 = slist[p], s1 = slist[p + 1], s2 = slist[p + 2], s3 = slist[p + 3];
        uint4 sv[4];
        #pragma unroll
        for (int u = 0; u < 4; ++u) sv[u] = *(const uint4*)(s8 + (size_t)(p + u) * 8);
        unsigned int xv0 = *(const unsigned int*)&xuph[(size_t)s0 * 128 + c];
        unsigned int xv1 = *(const unsigned int*)&xuph[(size_t)s1 * 128 + c];
        unsigned int xv2 = *(const unsigned int*)&xuph[(size_t)s2 * 128 + c];
        unsigned int xv3 = *(const unsigned int*)&xuph[(size_t)s3 * 128 + c];
        #pragma unroll
        for (int u = 0; u < 4; ++u) {
            const __half2* h2 = (const __half2*)&sv[u];
            float2 s01 = __half22float2(h2[0]);
            float2 s23 = __half22float2(h2[1]);
            float2 s45 = __half22float2(h2[2]);
            float2 s67 = __half22float2(h2[3]);
            float e0 = s01.x * w2c0[0] + s01.y * w2c0[1] + s23.x * w2c0[2] + s23.y * w2c0[3] +
                       s45.x * w2c0[4] + s45.y * w2c0[5] + s67.x * w2c0[6] + s67.y * w2c0[7];
            float e1 = s01.x * w2c1[0] + s01.y * w2c1[1] + s23.x * w2c1[2] + s23.y * w2c1[3] +
                       s45.x * w2c1[4] + s45.y * w2c1[5] + s67.x * w2c1[6] + s67.y * w2c1[7];
            float2 xf = bf2x2((u == 0) ? xv0 : (u == 1) ? xv1 : (u == 2) ? xv2 : xv3);
            a0 += xf.x * e0;
            a1 += xf.y * e1;
        }
    }
    for (; p < p1; ++p) {
        int src = slist[p];
        float2 xf = bf2x2(*(const unsigned int*)&xuph[(size_t)src * 128 + c]);
        const __half2* h2 = (const __half2*)(s8 + (size_t)p * 8);
        float2 s01 = __half22float2(h2[0]);
        float2 s23 = __half22float2(h2[1]);
        float2 s45 = __half22float2(h2[2]);
        float2 s67 = __half22float2(h2[3]);
        float e0 = s01.x * w2c0[0] + s01.y * w2c0[1] + s23.x * w2c0[2] + s23.y * w2c0[3] +
                   s45.x * w2c0[4] + s45.y * w2c0[5] + s67.x * w2c0[6] + s67.y * w2c0[7];
        float e1 = s01.x * w2c1[0] + s01.y * w2c1[1] + s23.x * w2c1[2] + s23.y * w2c1[3] +
                   s45.x * w2c1[4] + s45.y * w2c1[5] + s67.x * w2c1[6] + s67.y * w2c1[7];
        a0 += xf.x * e0;
        a1 += xf.y * e1;
    }
    float nx0 = x[(size_t)node * 128 + c] + a0;
    float nx1 = x[(size_t)node * 128 + c + 1] + a1;
    x[(size_t)node * 128 + c] = nx0;
    x[(size_t)node * 128 + c + 1] = nx1;
    *(unsigned int*)&xh[(size_t)node * 128 + c] = f2bf2(nx0, nx1);
}

// ---------------- pooling ----------------
__global__ __launch_bounds__(256) void k_pool(const float* __restrict__ P, const int* __restrict__ batch,
                                              float* __restrict__ pool, float* __restrict__ cnt, int n) {
    int i = blockIdx.x * 256 + threadIdx.x;
    int lane = threadIdx.x & 63;
    int b = (i < n) ? batch[i] : -1;
    float p = (i < n) ? P[i] : 0.f;
    int b0 = __shfl(b, 0, 64);
    int b63 = __shfl(b, 63, 64);
    if (b0 == b63 && b0 >= 0) {
        float s = p;
        #pragma unroll
        for (int off = 32; off > 0; off >>= 1) s += __shfl_xor(s, off, 64);
        if (lane == 0) {
            atomicAdd(&pool[b0], s);
            atomicAdd(&cnt[b0], 64.0f);
        }
    } else {
        if (i < n) {
            atomicAdd(&pool[b], p);
            atomicAdd(&cnt[b], 1.0f);
        }
    }
}

__global__ __launch_bounds__(64) void k_final(const float* __restrict__ pool, const float* __restrict__ cnt,
                                              float* __restrict__ out) {
    int g = threadIdx.x;
    if (g < G_) out[g] = __fdividef(pool[g], fmaxf(cnt[g], 1.0f));
}

extern "C" void kernel_launch(void* const* d_in, const int* in_sizes, int n_in,
                              void* d_out, int out_size, void* d_ws, size_t ws_size,
                              hipStream_t stream) {
    (void)in_sizes; (void)n_in; (void)out_size; (void)ws_size;
    const int* z = (const int*)d_in[0];
    const float* dist = (const float*)d_in[1];
    const float* dist_trip = (const float*)d_in[2];
    const float* angle = (const float*)d_in[3];
    const int* edge_index = (const int*)d_in[4];
    const int* triplets = (const int*)d_in[5];
    const int* batch = (const int*)d_in[6];
    const float* atom_table = (const float*)d_in[7];
    const float* rbf_freq = (const float*)d_in[8];
    const float* sbf_freq = (const float*)d_in[9];
    const float* emb_w1 = (const float*)d_in[10];
    const float* emb_b1 = (const float*)d_in[11];
    const float* emb_w2 = (const float*)d_in[12];
    const float* emb_b2 = (const float*)d_in[13];
    const float* iw_rbf1 = (const float*)d_in[14];
    const float* iw_rbf2 = (const float*)d_in[15];
    const float* iw_sbf1 = (const float*)d_in[16];
    const float* iw_sbf2 = (const float*)d_in[17];
    const float* iw_t1 = (const float*)d_in[18];
    const float* iw_t2 = (const float*)d_in[19];
    const float* ib_t2 = (const float*)d_in[20];
    const float* iw_up = (const float*)d_in[21];
    const float* ib_up = (const float*)d_in[22];
    const float* iw_down = (const float*)d_in[23];
    const float* ib_down = (const float*)d_in[24];
    const float* ow_rbf = (const float*)d_in[25];
    const float* ow0 = (const float*)d_in[26];
    const float* ob0 = (const float*)d_in[27];
    const float* ow1 = (const float*)d_in[28];
    const float* ob1 = (const float*)d_in[29];
    const float* ow2 = (const float*)d_in[30];
    const float* ob2 = (const float*)d_in[31];

    const int* erow = edge_index;
    const int* ecol = edge_index + E_;

    // workspace layout
    float* ws = (float*)d_ws;
    float* x = ws;                             // N*128
    float* bufA = x + (size_t)N_ * H_;         // N*128
    float* bufB = bufA + (size_t)N_ * H_;      // N*128
    float* P = bufB + (size_t)N_ * H_;         // N
    float* rbfS = P + N_;                      // E*6 (CSR order)
    float* SV = rbfS + (size_t)E_ * 6;         // N*8
    float* extra = SV + (size_t)N_ * 8;        // 128
    float* pool = extra + 128;                 // G
    float* cnt = pool + G_;                    // G
    int* deg = (int*)(cnt + G_);               // N
    int* rowptr = deg + N_;                    // N+1
    int* cur = rowptr + N_ + 1;                // N
    int* elist = cur + N_;                     // E
    int* slist = elist + E_;                   // E
    int* rowptrT = slist + E_;                 // N+1
    int* degT = rowptrT + N_ + 1;              // N
    float* dsort = (float*)(degT + N_);        // T
    float* asort = dsort + T_;                 // T
    __half* s8h = (__half*)(asort + T_);       // E*8 halves
    unsigned short* xh = (unsigned short*)(s8h + (size_t)E_ * 8);   // N*128 bf16 shadow of x
    unsigned short* xuph = xh + (size_t)N_ * H_;                    // N*128 bf16 shadow of x_up

    const int EG = (E_ + 255) / 256;
    const int TG = (T_ + 255) / 256;
    const int NG4 = (N_ + 3) / 4;
    const int GEMMG = (N_ + 127) / 128;

    hipMemsetAsync(deg, 0, N_ * sizeof(int), stream);
    hipMemsetAsync(degT, 0, N_ * sizeof(int), stream);
    k_count<<<EG, 256, 0, stream>>>(ecol, deg, E_);
    k_countT<<<TG, 256, 0, stream>>>(triplets, degT, T_);
    k_scan<<<1, 1024, 0, stream>>>(deg, rowptr, cur, N_);
    k_fill<<<EG, 256, 0, stream>>>(ecol, erow, cur, elist, slist, E_);
    k_scan<<<1, 1024, 0, stream>>>(degT, rowptrT, cur, N_);
    k_fillT<<<TG, 256, 0, stream>>>(triplets, cur, dist_trip, angle, dsort, asort, T_);

    k_rbfS<<<EG, 256, 0, stream>>>(elist, dist, rbf_freq, rbfS, E_);
    k_init_x<<<(N_ * 32) / 256, 256, 0, stream>>>(atom_table, z, x, N_);

    // embedding: x += segsum(silu(rbf@w1+b1)) @ w2 + deg*b2 ; writes bf16 shadow xh
    k_embS<<<NG4, 256, 0, stream>>>(rowptr, rbfS, emb_w1, emb_b1, bufA, N_);
    k_gemm<2, false, true, true><<<GEMMG, 256, 0, stream>>>(bufA, emb_w2, emb_b2, deg, x, xh, N_);

    auto out_block = [&](int k, bool first) {
        k_out_gather<<<NG4, 256, 0, stream>>>(rowptr, slist, rbfS, xh,
                                              ow_rbf + (size_t)k * 6 * 128, bufA, N_);
        k_gemm<1, true, false, false><<<GEMMG, 256, 0, stream>>>(bufA, ow0 + (size_t)k * 16384, ob0 + k * 128,
                                                                 nullptr, bufB, nullptr, N_);
        k_gemm<1, true, false, false><<<GEMMG, 256, 0, stream>>>(bufB, ow1 + (size_t)k * 16384, ob1 + k * 128,
                                                                 nullptr, bufA, nullptr, N_);
        if (first)
            k_p_acc<false><<<NG4, 256, 0, stream>>>(bufA, ow2 + k * 128, ob2 + k, P, N_);
        else
            k_p_acc<true><<<NG4, 256, 0, stream>>>(bufA, ow2 + k * 128, ob2 + k, P, N_);
    };

    out_block(0, true);

    for (int b = 0; b < 4; ++b) {
        k_gemm<1, false, false, false><<<GEMMG, 256, 0, stream>>>(x, iw_down + (size_t)b * 16384, ib_down + b * 128,
                                                                  nullptr, bufA, nullptr, N_);
        k_gemm<0, true, false, false><<<GEMMG, 256, 0, stream>>>(bufA, iw_t1 + (size_t)b * 16384, nullptr,
                                                                 nullptr, bufB, nullptr, N_);
        k_gemm<1, false, false, false><<<GEMMG, 256, 0, stream>>>(bufB, iw_t2 + (size_t)b * 16384, ib_t2 + b * 128,
                                                                  nullptr, bufA, nullptr, N_);
        k_trip_sv<<<(N_ * 8 + 255) / 256, 256, 0, stream>>>(rowptrT, dsort, asort, sbf_freq,
                                                            iw_sbf1 + (size_t)b * 192, SV, N_);
        k_sv_gemm<<<(N_ * 32) / 256, 256, 0, stream>>>(SV, iw_sbf2 + (size_t)b * 1024, bufB, N_);
        hipMemsetAsync(extra, 0, 128 * sizeof(float), stream);
        k_extra_reduce<<<128, 256, 0, stream>>>(bufA, bufB, extra, N_);
        k_s8h<<<EG, 256, 0, stream>>>(rbfS, iw_rbf1 + (size_t)b * 48, s8h, E_);
        // x_up with bf16 shadow, then fused gather + x/xh update
        k_gemm<1, false, false, true><<<GEMMG, 256, 0, stream>>>(x, iw_up + (size_t)b * 16384, ib_up + b * 128,
                                                                 nullptr, bufB, xuph, N_);
        k_interact<<<NG4, 256, 0, stream>>>(rowptr, slist, s8h, iw_rbf2 + (size_t)b * 1024, extra,
                                            xuph, x, xh, N_);
        out_block(b + 1, false);
    }

    hipMemsetAsync(pool, 0, 2 * G_ * sizeof(float), stream);
    k_pool<<<(N_ + 255) / 256, 256, 0, stream>>>(P, batch, pool, cnt, N_);
    k_final<<<1, 64, 0, stream>>>(pool, cnt, (float*)d_out);
}